// Round 11
// baseline (646.657 us; speedup 1.0000x reference)
//
#include <hip/hip_runtime.h>
#include <cstdint>
#include <cstddef>

#define S 108
#define NEMIT 126
#define T_LEN 2048
#define N_BATCH 256
#define MAXG 12    // max gather entries per lane after balancing
#define MAXNE 6500 // emission nnz upper bound (actual 6432)
#define NE_A 280   // A-matrix nnz

#define RESCALE_TARGET 1e24f
#define FLUSH_EPS 1e-30f

// ================= compile-time emission structure =================
struct EmTab {
  short row[MAXNE];
  short col[MAXNE];
  short widx[MAXNE];
  int rp[S + 1];
  int n;
  int nw;
};

constexpr int cmask(int sym, int add4) {
  int m = (sym == 4) ? 0xF : (1 << sym);
  if (add4) m |= 0x10;
  return m;
}

constexpr EmTab buildEm() {
  EmTab E{};
  int n = 0, k = 0;
  auto doCall = [&](int stt, int s0_, int s1_, int s2_, int xm_, int tr_) {
    const int m0 = cmask(s0_, xm_ < 2 ? 1 : 0);
    const int m1 = cmask(s1_, xm_ < 1 ? 1 : 0);
    const int m2 = cmask(s2_, 0);
    for (int x0 = 0; x0 < 5; x0++) {
      if (!((m0 >> x0) & 1)) continue;
      for (int x1 = 0; x1 < 5; x1++) {
        if (!((m1 >> x1) & 1)) continue;
        if (x0 != 4 && x1 == 4) continue;
        for (int x2 = 0; x2 < 5; x2++) {
          if (!((m2 >> x2) & 1)) continue;
          E.row[n] = (short)stt;
          E.col[n] = (short)(x0 * 25 + x1 * 5 + x2);
          E.widx[n] = (short)(tr_ ? k++ : -1);
          n++;
        }
      }
    }
  };
  doCall(0, 4, 4, 4, 0, 1);
  doCall(1, 4, 4, 0, 0, 1);
  doCall(2, 4, 0, 3, 0, 1);
  doCall(3, 0, 3, 2, 2, 0);
  doCall(4, 3, 2, 4, 2, 1);
  doCall(5, 2, 4, 4, 2, 1);
  for (int s = 6; s <= 51; s++) doCall(s, 4, 4, 4, 2, 1);
  doCall(52, 4, 4, 3, 2, 1);
  doCall(53, 4, 3, 0, 2, 1);
  doCall(53, 4, 3, 2, 2, 1);
  doCall(54, 3, 0, 0, 2, 0);
  doCall(54, 3, 0, 2, 2, 0);
  doCall(54, 3, 2, 0, 2, 0);
  doCall(55, 4, 4, 4, 2, 1);
  for (int s = 56; s <= 106; s++) doCall(s, 4, 4, 4, 2, 1);
  E.row[n] = 107; E.col[n] = 125; E.widx[n] = -1; n++;
  E.n = n; E.nw = k;
  for (int r = 0; r <= S; r++) E.rp[r] = 0;
  for (int e = 0; e < n; e++) E.rp[E.row[e] + 1]++;
  for (int r = 0; r < S; r++) E.rp[r + 1] += E.rp[r];
  return E;
}

constexpr EmTab EM_HOST = buildEm();
static_assert(EM_HOST.n <= MAXNE && EM_HOST.n > 6000, "emission count sanity");
__device__ const EmTab g_em = EM_HOST;

// ================= compile-time A structure + full gather plan =================
struct APlan {
  short vcode[NE_A], vwi[NE_A];
  short aidx[NE_A];
  short arp[S + 1];
  unsigned char src[64][MAXG];
  short a0[64][MAXG], a1[64][MAXG];
  unsigned char d0[64], d1[64], b0[64], b1[64];
  short o0[64], o1[64], scol[64];
  unsigned char sm1[64], sm2[64];
  int maxload, ncons, np;
};

constexpr APlan buildPlan() {
  APlan P{};
  short arow[NE_A] = {}, acol[NE_A] = {};
  int ne = 0;
  auto AD = [&](int r, int c, int code, int wi) {
    arow[ne] = (short)r; acol[ne] = (short)c;
    P.vcode[ne] = (short)code; P.vwi[ne] = (short)wi; ne++;
  };
  AD(0, 0, 2, 0); AD(0, 1, 1, 0); AD(1, 2, 0, 0); AD(2, 3, 0, 0);
  for (int i = 0; i < 16; i++) AD(3 + 3 * i, 4 + 3 * i, 1, 1 + i);
  for (int i = 0; i < 16; i++) AD(4 + 3 * i, 5 + 3 * i, 0, 0);
  for (int i = 0; i < 16; i++) AD(5 + 3 * i, 6 + 3 * i, 0, 0);
  for (int i = 0; i <= 16; i++) AD(3 + 3 * i, 56 + 3 * i, 1, 17 + i);
  AD(51, 52, 1, 34);
  for (int i = 0; i <= 16; i++) AD(56 + 3 * i, 57 + 3 * i, 0, 0);
  for (int i = 0; i <= 16; i++) AD(57 + 3 * i, 58 + 3 * i, 0, 0);
  for (int i = 0; i <= 16; i++) AD(58 + 3 * i, 4 + 3 * i, 1, 35 + i);
  for (int i = 0; i <= 16; i++) AD(58 + 3 * i, 56 + 3 * i, 2, 35 + i);
  for (int a = 0; a < 16; a++)
    for (int jj = a + 1; jj <= 16; jj++) AD(3 + 3 * a, 4 + 3 * jj, 3, jj - a + 1);
  AD(52, 53, 0, 0); AD(53, 54, 0, 0); AD(54, 55, 0, 0);
  AD(55, 55, 0, 0); AD(55, 107, 0, 0); AD(107, 107, 0, 0);

  int rc[S + 1] = {};
  for (int e = 0; e < ne; e++) rc[arow[e] + 1]++;
  for (int r = 0; r < S; r++) rc[r + 1] += rc[r];
  for (int r = 0; r <= S; r++) P.arp[r] = (short)rc[r];
  int fill[S] = {};
  for (int e = 0; e < ne; e++) { const int r = arow[e]; P.aidx[rc[r] + fill[r]] = (short)e; fill[r]++; }

  int ccnt[S] = {}; short clist[S][18] = {};
  for (int e = 0; e < ne; e++) { const int c = acol[e]; clist[c][ccnt[c]] = (short)e; ccnt[c]++; }
  int npcA[S] = {};
  short pdefs[16][6] = {}; int pcnt[16] = {}; short pcol[16] = {};
  int np = 0;
  for (int c = 0; c < S; c++) {
    while (ccnt[c] > 8) {
      const int base = ccnt[c] - 6;
      for (int j = 0; j < 6; j++) pdefs[np][j] = clist[c][base + j];
      pcnt[np] = 6; pcol[np] = (short)c;
      npcA[c]++; ccnt[c] -= 6; np++;
    }
  }
  int lload[64] = {}, lnit[64] = {};
  for (int l = 0; l < 64; l++) {
    for (int e = 0; e < MAXG; e++) { P.src[l][e] = 0; P.a0[l][e] = -1; P.a1[l][e] = -1; }
    P.d0[l] = 127; P.d1[l] = 127; P.b0[l] = 0; P.b1[l] = 0;
    P.o0[l] = -1; P.o1[l] = -1; P.scol[l] = -1; P.sm1[l] = 0; P.sm2[l] = 0;
  }
  int ncons = 0;
  for (int c = 0; c < S; c++) {
    if (ccnt[c] == 1) {
      const int e0 = clist[c][0];
      const int r = arow[e0];
      if (npcA[r] > 0) {
        const int l = 54 + ncons; ncons++;
        int k = 0;
        P.src[l][k] = (unsigned char)r; P.a0[l][k] = (short)e0; k++;
        for (int p = 0; p < np; p++)
          if (pcol[p] == r) { P.src[l][k] = (unsigned char)(108 + p); P.a0[l][k] = (short)e0; k++; }
        P.d0[l] = (unsigned char)c; P.b0[l] = (unsigned char)c; P.o0[l] = (short)c;
        P.scol[l] = (short)r;
        P.sm1[l] = (k >= 2) ? 1 : 0; P.sm2[l] = (k >= 3) ? 1 : 0;
        lload[l] = k; lnit[l] = 1;
        ccnt[c] = 0;
      }
    }
  }
  int rr = 0;
  auto pickLane = [&](int L) {
    for (;;) {
      const int pos = rr & 127; rr++;
      const int l = (pos < 64) ? pos : (127 - pos);
      if (lnit[l] < 2 && lload[l] + L <= MAXG) return l;
    }
  };
  for (int th = 8; th >= 1; th--) {
    for (int p = 0; p < np; p++) {
      if (pcnt[p] != th) continue;
      const int l = pickLane(th);
      const int it = lnit[l], base = lload[l];
      for (int j = 0; j < th; j++) {
        P.src[l][base + j] = (unsigned char)arow[pdefs[p][j]];
        if (it == 0) P.a0[l][base + j] = pdefs[p][j];
        else         P.a1[l][base + j] = pdefs[p][j];
      }
      if (it == 0) { P.d0[l] = (unsigned char)(108 + p); P.b0[l] = (unsigned char)pcol[p]; P.o0[l] = -1; }
      else         { P.d1[l] = (unsigned char)(108 + p); P.b1[l] = (unsigned char)pcol[p]; P.o1[l] = -1; }
      lload[l] = base + th; lnit[l] = it + 1;
    }
    for (int c = 0; c < S; c++) {
      if (ccnt[c] != th) continue;
      const int l = pickLane(th);
      const int it = lnit[l], base = lload[l];
      for (int j = 0; j < th; j++) {
        P.src[l][base + j] = (unsigned char)arow[clist[c][j]];
        if (it == 0) P.a0[l][base + j] = clist[c][j];
        else         P.a1[l][base + j] = clist[c][j];
      }
      const short oc = (npcA[c] > 0) ? (short)-1 : (short)c;
      if (it == 0) { P.d0[l] = (unsigned char)c; P.b0[l] = (unsigned char)c; P.o0[l] = oc; }
      else         { P.d1[l] = (unsigned char)c; P.b1[l] = (unsigned char)c; P.o1[l] = oc; }
      lload[l] = base + th; lnit[l] = it + 1;
    }
  }
  int ml = 0;
  for (int l = 0; l < 64; l++) ml = (lload[l] > ml) ? lload[l] : ml;
  P.maxload = ml; P.ncons = ncons; P.np = np;
  return P;
}

constexpr APlan PLAN_HOST = buildPlan();
static_assert(PLAN_HOST.maxload <= MAXG, "lane gather overflow");
static_assert(PLAN_HOST.ncons <= 10, "too many consumer lanes");
static_assert(PLAN_HOST.np <= 16, "too many pieces");
__device__ const APlan g_plan = PLAN_HOST;

// One scan step. SYM: symbol (register). ROWS: ring row slot (0..31) of row t.
// PREVROWS: ring row slot of row t-1. IS_LAST: compile-time-foldable rescale flag.
// DO_SCOL: whether to emit the split-col write for row t-1.
#define STEP_BODY(SYM, ROWS, PREVROWS, IS_LAST, DO_SCOL)                         \
  {                                                                              \
    const int ecur_ = (SYM);                                                     \
    const float bt0 = Bt_lds[ecur_ * S + b0c];                                   \
    const float bt1 = Bt_lds[ecur_ * S + b1c];                                   \
    float x[MAXG];                                                               \
    _Pragma("unroll")                                                            \
    for (int e = 0; e < MAXG; e++) x[e] = alpha_lds[gsrc[e]];                    \
    float aA = 0.f, aB = 0.f, bA = 0.f, bB = 0.f;                                \
    _Pragma("unroll")                                                            \
    for (int e = 0; e < MAXG; e += 2) {                                          \
      aA += x[e] * w0v[e];     aB += x[e + 1] * w0v[e + 1];                      \
      bA += x[e] * w1v[e];     bB += x[e + 1] * w1v[e + 1];                      \
    }                                                                            \
    u0 = (aA + aB) * bt0;                                                        \
    u1 = (bA + bB) * bt1;                                                        \
    const float sumv_ = x[0] + sm1 * x[1] + sm2 * x[2];                          \
    u0 = (u0 >= FLUSH_EPS) ? u0 : 0.f;                                           \
    u1 = (u1 >= FLUSH_EPS) ? u1 : 0.f;                                           \
    if (IS_LAST) {                                                               \
      float m_ = fmaxf(u0, u1);                                                  \
      _Pragma("unroll")                                                          \
      for (int msk = 1; msk < 64; msk <<= 1)                                     \
        m_ = fmaxf(m_, __shfl_xor(m_, msk, 64));                                 \
      const float r_ = RESCALE_TARGET / m_;                                      \
      u0 *= r_; u1 *= r_;                                                        \
    }                                                                            \
    alpha_lds[d0] = u0;                                                          \
    alpha_lds[d1] = u1;                                                          \
    const int rs_ = (ROWS)*S;                                                    \
    if (o0 >= 0) ring[rs_ + o0] = u0;                                            \
    if (o1 >= 0) ring[rs_ + o1] = u1;                                            \
    if (DO_SCOL && scol >= 0) ring[(PREVROWS)*S + scol] = sumv_;                 \
  }

// ================= scan kernel: producer wave + normalizing consumer ===========
__global__ __launch_bounds__(128, 1) void hmm_scan_kernel(
    const int* __restrict__ inp, const float* __restrict__ w,
    const float* __restrict__ ek, const float* __restrict__ ik,
    float* __restrict__ out) {
  __shared__ __align__(16) float Bt_lds[NEMIT * S];
  __shared__ __align__(16) float ring[32 * S];   // 32-row output ring (2 halves)
  __shared__ float alpha_lds[128];               // 108 states + piece slots + trash
  __shared__ float pi_lds[S];
  __shared__ float avalS[NE_A];
  __shared__ float inv_lds[16];                  // consumer-only row inverses
  __shared__ __align__(16) int seq_lds[T_LEN];   // whole symbol sequence (8 KB)

  const int tid = threadIdx.x;
  const int lid = tid & 63;
  const int wv = tid >> 6;   // 0 = producer, 1 = consumer

  // ---------- setup (both waves cooperate) ----------
  for (int i = tid; i < NEMIT * S; i += 128) Bt_lds[i] = 0.f;

  {  // seq -> LDS (int4 loads)
    const int4* s4 = (const int4*)(inp + (size_t)blockIdx.x * T_LEN);
    int4* d4 = (int4*)seq_lds;
    for (int i = tid; i < T_LEN / 4; i += 128) d4[i] = s4[i];
  }

  if (wv == 0) {  // pi = softmax(ik)
    float q0 = ik[lid];
    float q1 = (lid + 64 < S) ? ik[lid + 64] : -1e30f;
    float mx = fmaxf(q0, q1);
#pragma unroll
    for (int msk = 1; msk < 64; msk <<= 1) mx = fmaxf(mx, __shfl_xor(mx, msk, 64));
    float e0v = expf(q0 - mx);
    float e1v = (lid + 64 < S) ? expf(q1 - mx) : 0.f;
    float zz = e0v + e1v;
#pragma unroll
    for (int msk = 1; msk < 64; msk <<= 1) zz += __shfl_xor(zz, msk, 64);
    const float rz = 1.f / zz;
    pi_lds[lid] = e0v * rz;
    if (lid + 64 < S) pi_lds[lid + 64] = e1v * rz;
  }

  {  // A values from descriptors
    const float wk = w[52];
    const float aw = fabsf(wk);
    const float sgnw = (wk > 0.f) ? 1.f : ((wk < 0.f) ? -1.f : 0.f);
    for (int e = tid; e < NE_A; e += 128) {
      const int code = g_plan.vcode[e];
      const int wi = g_plan.vwi[e];
      float v;
      if (code == 0) v = 1.f;
      else if (code == 1) v = w[wi];
      else if (code == 2) v = 1.f - w[wi];
      else {
        const float pw = powf(aw, (float)wi);
        v = 1.f - ((wi & 1) ? sgnw : 1.f) * pw;
      }
      avalS[e] = v;
    }
  }
  __syncthreads();

  if (tid < S) {  // A row-softmax
    const int b = g_plan.arp[tid], e2 = g_plan.arp[tid + 1];
    float m = -1e30f;
    for (int j = b; j < e2; j++) m = fmaxf(m, avalS[g_plan.aidx[j]]);
    float z = 0.f;
    for (int j = b; j < e2; j++) z += expf(avalS[g_plan.aidx[j]] - m);
    const float rz = 1.f / z;
    for (int j = b; j < e2; j++) {
      const int ii = g_plan.aidx[j];
      avalS[ii] = expf(avalS[ii] - m) * rz;
    }
  }
  __syncthreads();

  if (tid < S) {  // B row-softmax
    const int r = tid;
    const int b = g_em.rp[r], e2 = g_em.rp[r + 1];
    float m = -1e30f;
    for (int e = b; e < e2; e++) {
      const int wi = g_em.widx[e];
      m = fmaxf(m, (wi >= 0) ? ek[wi] : 1.f);
    }
    float z = 0.f;
    for (int e = b; e < e2; e++) {
      const int wi = g_em.widx[e];
      z += expf(((wi >= 0) ? ek[wi] : 1.f) - m);
    }
    const float rz = 1.f / z;
    for (int e = b; e < e2; e++) {
      const int wi = g_em.widx[e];
      Bt_lds[(int)g_em.col[e] * S + r] = expf(((wi >= 0) ? ek[wi] : 1.f) - m) * rz;
    }
  }

  // plan -> registers
  int gsrc[MAXG]; float w0v[MAXG], w1v[MAXG];
#pragma unroll
  for (int e = 0; e < MAXG; e++) {
    gsrc[e] = g_plan.src[lid][e];
    const int a0 = g_plan.a0[lid][e], a1 = g_plan.a1[lid][e];
    w0v[e] = (a0 >= 0) ? avalS[a0] : 0.f;
    w1v[e] = (a1 >= 0) ? avalS[a1] : 0.f;
  }
  const int d0 = g_plan.d0[lid], d1 = g_plan.d1[lid];
  const int b0c = g_plan.b0[lid], b1c = g_plan.b1[lid];
  const int o0 = g_plan.o0[lid], o1 = g_plan.o1[lid];
  const int scol = g_plan.scol[lid];
  const float sm1 = (float)g_plan.sm1[lid], sm2 = (float)g_plan.sm2[lid];
  __syncthreads();   // Bt_lds, avalS, seq_lds final

  float* ob = out + (size_t)blockIdx.x * T_LEN * S;
  float u0 = 0.f, u1 = 0.f;

  // ---------- group 0 (producer): init row 0, steps 1..15 ----------
  if (wv == 0) {
    const int e0s = seq_lds[0];
    const float ui0 = (d0 < 108) ? RESCALE_TARGET * pi_lds[d0] * Bt_lds[e0s * S + d0] : 0.f;
    const float ui1 = (d1 < 108) ? RESCALE_TARGET * pi_lds[d1] * Bt_lds[e0s * S + d1] : 0.f;
    alpha_lds[d0] = ui0;
    alpha_lds[d1] = ui1;
    for (int i = lid; i < S; i += 64) ring[i] = alpha_lds[i];

    int syms[16];
    const int4* sp = (const int4*)&seq_lds[0];
#pragma unroll
    for (int q = 0; q < 4; q++) {
      const int4 v = sp[q];
      syms[4 * q + 0] = v.x; syms[4 * q + 1] = v.y;
      syms[4 * q + 2] = v.z; syms[4 * q + 3] = v.w;
    }
#pragma unroll
    for (int j = 1; j < 16; j++) {
      STEP_BODY(syms[j], j, j - 1, j == 15, 1);
    }
    if (scol >= 0) {
      const float x0 = alpha_lds[gsrc[0]];
      const float x1 = alpha_lds[gsrc[1]];
      const float x2 = alpha_lds[gsrc[2]];
      ring[15 * S + scol] = x0 + sm1 * x1 + sm2 * x2;
    }
  }
  __syncthreads();

  // ---------- main: producer group k (k<128); consumer drains+normalizes k-1 ---
  for (int k = 1; k <= 128; k++) {
    if (wv == 0) {
      if (k < 128) {
        const int half = (k & 1) << 4;   // ring row base (0 or 16)
        const int phal = ((k - 1) & 1) << 4;
        int syms[16];
        const int4* sp = (const int4*)&seq_lds[16 * k];
#pragma unroll
        for (int q = 0; q < 4; q++) {
          const int4 v = sp[q];
          syms[4 * q + 0] = v.x; syms[4 * q + 1] = v.y;
          syms[4 * q + 2] = v.z; syms[4 * q + 3] = v.w;
        }
#pragma unroll
        for (int j = 0; j < 16; j++) {
          // j==0: row t-1 belongs to the half being drained -> skip scol write
          STEP_BODY(syms[j], half + j, (j == 0) ? (phal + 15) : (half + j - 1),
                    j == 15, j != 0);
        }
        if (scol >= 0) {
          const float x0 = alpha_lds[gsrc[0]];
          const float x1 = alpha_lds[gsrc[1]];
          const float x2 = alpha_lds[gsrc[2]];
          ring[(half + 15) * S + scol] = x0 + sm1 * x1 + sm2 * x2;
        }
      }
    } else {
      const int g = k - 1;
      const float* srcb = &ring[(g & 1) * 16 * S];
      float* dstb = ob + (size_t)g * 16 * S;
      // row inverse sums
#pragma unroll
      for (int r = 0; r < 16; r++) {
        float sv = srcb[r * S + lid];
        if (lid + 64 < S) sv += srcb[r * S + lid + 64];
#pragma unroll
        for (int msk = 1; msk < 64; msk <<= 1) sv += __shfl_xor(sv, msk, 64);
        if (lid == 0) inv_lds[r] = 1.f / sv;
      }
      // normalize + coalesced store
#pragma unroll
      for (int k2 = 0; k2 < 7; k2++) {
        const int i4 = k2 * 64 + lid;
        if (i4 < 27 * 16) {
          float4 v = ((const float4*)srcb)[i4];
          const float iv = inv_lds[i4 / 27];
          v.x *= iv; v.y *= iv; v.z *= iv; v.w *= iv;
          ((float4*)dstb)[i4] = v;
        }
      }
    }
    __syncthreads();
  }
}

extern "C" void kernel_launch(void* const* d_in, const int* in_sizes, int n_in,
                              void* d_out, int out_size, void* d_ws, size_t ws_size,
                              hipStream_t stream) {
  const int* inp = (const int*)d_in[0];
  const float* w = (const float*)d_in[1];
  const float* ek = (const float*)d_in[2];
  const float* ik = (const float*)d_in[3];
  float* out = (float*)d_out;
  (void)d_ws; (void)ws_size; (void)in_sizes; (void)n_in; (void)out_size;
  hmm_scan_kernel<<<N_BATCH, 128, 0, stream>>>(inp, w, ek, ik, out);
}

// Round 12
// 639.214 us; speedup vs baseline: 1.0116x; 1.0116x over previous
//
#include <hip/hip_runtime.h>
#include <cstdint>
#include <cstddef>

#define S 108
#define NEMIT 126
#define T_LEN 2048
#define N_BATCH 256
#define MAXG 12    // max gather entries per lane after balancing
#define MAXNE 6500 // emission nnz upper bound (actual 6432)
#define NE_A 280   // A-matrix nnz

#define RESCALE_TARGET 1e24f
#define FLUSH_EPS 1e-30f

// ================= compile-time emission structure =================
struct EmTab {
  short row[MAXNE];
  short col[MAXNE];
  short widx[MAXNE];
  int rp[S + 1];
  int n;
  int nw;
};

constexpr int cmask(int sym, int add4) {
  int m = (sym == 4) ? 0xF : (1 << sym);
  if (add4) m |= 0x10;
  return m;
}

constexpr EmTab buildEm() {
  EmTab E{};
  int n = 0, k = 0;
  auto doCall = [&](int stt, int s0_, int s1_, int s2_, int xm_, int tr_) {
    const int m0 = cmask(s0_, xm_ < 2 ? 1 : 0);
    const int m1 = cmask(s1_, xm_ < 1 ? 1 : 0);
    const int m2 = cmask(s2_, 0);
    for (int x0 = 0; x0 < 5; x0++) {
      if (!((m0 >> x0) & 1)) continue;
      for (int x1 = 0; x1 < 5; x1++) {
        if (!((m1 >> x1) & 1)) continue;
        if (x0 != 4 && x1 == 4) continue;
        for (int x2 = 0; x2 < 5; x2++) {
          if (!((m2 >> x2) & 1)) continue;
          E.row[n] = (short)stt;
          E.col[n] = (short)(x0 * 25 + x1 * 5 + x2);
          E.widx[n] = (short)(tr_ ? k++ : -1);
          n++;
        }
      }
    }
  };
  doCall(0, 4, 4, 4, 0, 1);
  doCall(1, 4, 4, 0, 0, 1);
  doCall(2, 4, 0, 3, 0, 1);
  doCall(3, 0, 3, 2, 2, 0);
  doCall(4, 3, 2, 4, 2, 1);
  doCall(5, 2, 4, 4, 2, 1);
  for (int s = 6; s <= 51; s++) doCall(s, 4, 4, 4, 2, 1);
  doCall(52, 4, 4, 3, 2, 1);
  doCall(53, 4, 3, 0, 2, 1);
  doCall(53, 4, 3, 2, 2, 1);
  doCall(54, 3, 0, 0, 2, 0);
  doCall(54, 3, 0, 2, 2, 0);
  doCall(54, 3, 2, 0, 2, 0);
  doCall(55, 4, 4, 4, 2, 1);
  for (int s = 56; s <= 106; s++) doCall(s, 4, 4, 4, 2, 1);
  E.row[n] = 107; E.col[n] = 125; E.widx[n] = -1; n++;
  E.n = n; E.nw = k;
  for (int r = 0; r <= S; r++) E.rp[r] = 0;
  for (int e = 0; e < n; e++) E.rp[E.row[e] + 1]++;
  for (int r = 0; r < S; r++) E.rp[r + 1] += E.rp[r];
  return E;
}

constexpr EmTab EM_HOST = buildEm();
static_assert(EM_HOST.n <= MAXNE && EM_HOST.n > 6000, "emission count sanity");
__device__ const EmTab g_em = EM_HOST;

// ================= compile-time A structure + full gather plan =================
struct APlan {
  short vcode[NE_A], vwi[NE_A];
  short aidx[NE_A];
  short arp[S + 1];
  unsigned char src[64][MAXG];
  short a0[64][MAXG], a1[64][MAXG];
  unsigned char d0[64], d1[64], b0[64], b1[64];
  short o0[64], o1[64], scol[64];
  unsigned char sm1[64], sm2[64];
  int maxload, ncons, np;
};

constexpr APlan buildPlan() {
  APlan P{};
  short arow[NE_A] = {}, acol[NE_A] = {};
  int ne = 0;
  auto AD = [&](int r, int c, int code, int wi) {
    arow[ne] = (short)r; acol[ne] = (short)c;
    P.vcode[ne] = (short)code; P.vwi[ne] = (short)wi; ne++;
  };
  AD(0, 0, 2, 0); AD(0, 1, 1, 0); AD(1, 2, 0, 0); AD(2, 3, 0, 0);
  for (int i = 0; i < 16; i++) AD(3 + 3 * i, 4 + 3 * i, 1, 1 + i);
  for (int i = 0; i < 16; i++) AD(4 + 3 * i, 5 + 3 * i, 0, 0);
  for (int i = 0; i < 16; i++) AD(5 + 3 * i, 6 + 3 * i, 0, 0);
  for (int i = 0; i <= 16; i++) AD(3 + 3 * i, 56 + 3 * i, 1, 17 + i);
  AD(51, 52, 1, 34);
  for (int i = 0; i <= 16; i++) AD(56 + 3 * i, 57 + 3 * i, 0, 0);
  for (int i = 0; i <= 16; i++) AD(57 + 3 * i, 58 + 3 * i, 0, 0);
  for (int i = 0; i <= 16; i++) AD(58 + 3 * i, 4 + 3 * i, 1, 35 + i);
  for (int i = 0; i <= 16; i++) AD(58 + 3 * i, 56 + 3 * i, 2, 35 + i);
  for (int a = 0; a < 16; a++)
    for (int jj = a + 1; jj <= 16; jj++) AD(3 + 3 * a, 4 + 3 * jj, 3, jj - a + 1);
  AD(52, 53, 0, 0); AD(53, 54, 0, 0); AD(54, 55, 0, 0);
  AD(55, 55, 0, 0); AD(55, 107, 0, 0); AD(107, 107, 0, 0);

  int rc[S + 1] = {};
  for (int e = 0; e < ne; e++) rc[arow[e] + 1]++;
  for (int r = 0; r < S; r++) rc[r + 1] += rc[r];
  for (int r = 0; r <= S; r++) P.arp[r] = (short)rc[r];
  int fill[S] = {};
  for (int e = 0; e < ne; e++) { const int r = arow[e]; P.aidx[rc[r] + fill[r]] = (short)e; fill[r]++; }

  int ccnt[S] = {}; short clist[S][18] = {};
  for (int e = 0; e < ne; e++) { const int c = acol[e]; clist[c][ccnt[c]] = (short)e; ccnt[c]++; }
  int npcA[S] = {};
  short pdefs[16][6] = {}; int pcnt[16] = {}; short pcol[16] = {};
  int np = 0;
  for (int c = 0; c < S; c++) {
    while (ccnt[c] > 8) {
      const int base = ccnt[c] - 6;
      for (int j = 0; j < 6; j++) pdefs[np][j] = clist[c][base + j];
      pcnt[np] = 6; pcol[np] = (short)c;
      npcA[c]++; ccnt[c] -= 6; np++;
    }
  }
  int lload[64] = {}, lnit[64] = {};
  for (int l = 0; l < 64; l++) {
    for (int e = 0; e < MAXG; e++) { P.src[l][e] = 0; P.a0[l][e] = -1; P.a1[l][e] = -1; }
    P.d0[l] = 127; P.d1[l] = 127; P.b0[l] = 0; P.b1[l] = 0;
    P.o0[l] = -1; P.o1[l] = -1; P.scol[l] = -1; P.sm1[l] = 0; P.sm2[l] = 0;
  }
  int ncons = 0;
  for (int c = 0; c < S; c++) {
    if (ccnt[c] == 1) {
      const int e0 = clist[c][0];
      const int r = arow[e0];
      if (npcA[r] > 0) {
        const int l = 54 + ncons; ncons++;
        int k = 0;
        P.src[l][k] = (unsigned char)r; P.a0[l][k] = (short)e0; k++;
        for (int p = 0; p < np; p++)
          if (pcol[p] == r) { P.src[l][k] = (unsigned char)(108 + p); P.a0[l][k] = (short)e0; k++; }
        P.d0[l] = (unsigned char)c; P.b0[l] = (unsigned char)c; P.o0[l] = (short)c;
        P.scol[l] = (short)r;
        P.sm1[l] = (k >= 2) ? 1 : 0; P.sm2[l] = (k >= 3) ? 1 : 0;
        lload[l] = k; lnit[l] = 1;
        ccnt[c] = 0;
      }
    }
  }
  int rr = 0;
  auto pickLane = [&](int L) {
    for (;;) {
      const int pos = rr & 127; rr++;
      const int l = (pos < 64) ? pos : (127 - pos);
      if (lnit[l] < 2 && lload[l] + L <= MAXG) return l;
    }
  };
  for (int th = 8; th >= 1; th--) {
    for (int p = 0; p < np; p++) {
      if (pcnt[p] != th) continue;
      const int l = pickLane(th);
      const int it = lnit[l], base = lload[l];
      for (int j = 0; j < th; j++) {
        P.src[l][base + j] = (unsigned char)arow[pdefs[p][j]];
        if (it == 0) P.a0[l][base + j] = pdefs[p][j];
        else         P.a1[l][base + j] = pdefs[p][j];
      }
      if (it == 0) { P.d0[l] = (unsigned char)(108 + p); P.b0[l] = (unsigned char)pcol[p]; P.o0[l] = -1; }
      else         { P.d1[l] = (unsigned char)(108 + p); P.b1[l] = (unsigned char)pcol[p]; P.o1[l] = -1; }
      lload[l] = base + th; lnit[l] = it + 1;
    }
    for (int c = 0; c < S; c++) {
      if (ccnt[c] != th) continue;
      const int l = pickLane(th);
      const int it = lnit[l], base = lload[l];
      for (int j = 0; j < th; j++) {
        P.src[l][base + j] = (unsigned char)arow[clist[c][j]];
        if (it == 0) P.a0[l][base + j] = clist[c][j];
        else         P.a1[l][base + j] = clist[c][j];
      }
      const short oc = (npcA[c] > 0) ? (short)-1 : (short)c;
      if (it == 0) { P.d0[l] = (unsigned char)c; P.b0[l] = (unsigned char)c; P.o0[l] = oc; }
      else         { P.d1[l] = (unsigned char)c; P.b1[l] = (unsigned char)c; P.o1[l] = oc; }
      lload[l] = base + th; lnit[l] = it + 1;
    }
  }
  int ml = 0;
  for (int l = 0; l < 64; l++) ml = (lload[l] > ml) ? lload[l] : ml;
  P.maxload = ml; P.ncons = ncons; P.np = np;
  return P;
}

constexpr APlan PLAN_HOST = buildPlan();
static_assert(PLAN_HOST.maxload <= MAXG, "lane gather overflow");
static_assert(PLAN_HOST.ncons <= 10, "too many consumer lanes");
static_assert(PLAN_HOST.np <= 16, "too many pieces");
__device__ const APlan g_plan = PLAN_HOST;

// ================= scan kernel: R10 producer + normalizing consumer ============
__global__ __launch_bounds__(128, 1) void hmm_scan_kernel(
    const int* __restrict__ inp, const float* __restrict__ w,
    const float* __restrict__ ek, const float* __restrict__ ik,
    float* __restrict__ out) {
  __shared__ __align__(16) float Bt_lds[NEMIT * S];
  __shared__ __align__(16) float ring[32 * S];   // 32-row output ring (2 halves)
  __shared__ float alpha_lds[128];               // 108 states + piece slots + trash
  __shared__ float pi_lds[S];
  __shared__ float avalS[NE_A];
  __shared__ float inv_lds[16];                  // consumer-only row inverses
  __shared__ __align__(16) int seq_lds[T_LEN];   // whole symbol sequence (8 KB)

  const int tid = threadIdx.x;
  const int lid = tid & 63;
  const int wv = tid >> 6;   // 0 = producer, 1 = consumer

  // ---------- setup (both waves cooperate) ----------
  for (int i = tid; i < NEMIT * S; i += 128) Bt_lds[i] = 0.f;

  {  // seq -> LDS (int4 loads)
    const int4* s4 = (const int4*)(inp + (size_t)blockIdx.x * T_LEN);
    int4* d4 = (int4*)seq_lds;
    for (int i = tid; i < T_LEN / 4; i += 128) d4[i] = s4[i];
  }

  if (wv == 0) {  // pi = softmax(ik), single wave (shfl)
    float q0 = ik[lid];
    float q1 = (lid + 64 < S) ? ik[lid + 64] : -1e30f;
    float mx = fmaxf(q0, q1);
#pragma unroll
    for (int msk = 1; msk < 64; msk <<= 1) mx = fmaxf(mx, __shfl_xor(mx, msk, 64));
    float e0v = expf(q0 - mx);
    float e1v = (lid + 64 < S) ? expf(q1 - mx) : 0.f;
    float zz = e0v + e1v;
#pragma unroll
    for (int msk = 1; msk < 64; msk <<= 1) zz += __shfl_xor(zz, msk, 64);
    const float rz = 1.f / zz;
    pi_lds[lid] = e0v * rz;
    if (lid + 64 < S) pi_lds[lid + 64] = e1v * rz;
  }

  {  // A values from descriptors, parallel across 128 threads
    const float wk = w[52];
    const float aw = fabsf(wk);
    const float sgnw = (wk > 0.f) ? 1.f : ((wk < 0.f) ? -1.f : 0.f);
    for (int e = tid; e < NE_A; e += 128) {
      const int code = g_plan.vcode[e];
      const int wi = g_plan.vwi[e];
      float v;
      if (code == 0) v = 1.f;
      else if (code == 1) v = w[wi];
      else if (code == 2) v = 1.f - w[wi];
      else {
        const float pw = powf(aw, (float)wi);
        v = 1.f - ((wi & 1) ? sgnw : 1.f) * pw;
      }
      avalS[e] = v;
    }
  }
  __syncthreads();

  // A row-softmax (one row per thread, 108 < 128)
  if (tid < S) {
    const int b = g_plan.arp[tid], e2 = g_plan.arp[tid + 1];
    float m = -1e30f;
    for (int j = b; j < e2; j++) m = fmaxf(m, avalS[g_plan.aidx[j]]);
    float z = 0.f;
    for (int j = b; j < e2; j++) z += expf(avalS[g_plan.aidx[j]] - m);
    const float rz = 1.f / z;
    for (int j = b; j < e2; j++) {
      const int ii = g_plan.aidx[j];
      avalS[ii] = expf(avalS[ii] - m) * rz;
    }
  }
  __syncthreads();

  // B row-softmax (one row per thread)
  if (tid < S) {
    const int r = tid;
    const int b = g_em.rp[r], e2 = g_em.rp[r + 1];
    float m = -1e30f;
    for (int e = b; e < e2; e++) {
      const int wi = g_em.widx[e];
      m = fmaxf(m, (wi >= 0) ? ek[wi] : 1.f);
    }
    float z = 0.f;
    for (int e = b; e < e2; e++) {
      const int wi = g_em.widx[e];
      z += expf(((wi >= 0) ? ek[wi] : 1.f) - m);
    }
    const float rz = 1.f / z;
    for (int e = b; e < e2; e++) {
      const int wi = g_em.widx[e];
      Bt_lds[(int)g_em.col[e] * S + r] = expf(((wi >= 0) ? ek[wi] : 1.f) - m) * rz;
    }
  }

  // plan -> registers (indexed by lane; wave 1 loads too, unused)
  int gsrc[MAXG]; float w0v[MAXG], w1v[MAXG];
#pragma unroll
  for (int e = 0; e < MAXG; e++) {
    gsrc[e] = g_plan.src[lid][e];
    const int a0 = g_plan.a0[lid][e], a1 = g_plan.a1[lid][e];
    w0v[e] = (a0 >= 0) ? avalS[a0] : 0.f;
    w1v[e] = (a1 >= 0) ? avalS[a1] : 0.f;
  }
  const int d0 = g_plan.d0[lid], d1 = g_plan.d1[lid];
  const int b0c = g_plan.b0[lid], b1c = g_plan.b1[lid];
  const int o0 = g_plan.o0[lid], o1 = g_plan.o1[lid];
  const int scol = g_plan.scol[lid];
  const float sm1 = (float)g_plan.sm1[lid], sm2 = (float)g_plan.sm2[lid];
  __syncthreads();   // Bt_lds, avalS, seq_lds final

  float* ob = out + (size_t)blockIdx.x * T_LEN * S;
  int etn = 0;
  float u0 = 0.f, u1 = 0.f;

  if (wv == 0) {  // init: row 0 into alpha + ring row 0
    const int e0s = seq_lds[0];
    const float ui0 = (d0 < 108) ? RESCALE_TARGET * pi_lds[d0] * Bt_lds[e0s * S + d0] : 0.f;
    const float ui1 = (d1 < 108) ? RESCALE_TARGET * pi_lds[d1] * Bt_lds[e0s * S + d1] : 0.f;
    alpha_lds[d0] = ui0;
    alpha_lds[d1] = ui1;
    for (int i = lid; i < S; i += 64) ring[i] = alpha_lds[i];   // same-wave order OK
    etn = seq_lds[1];
  }

  // ---------- main: producer fills group k (k<128); consumer drains+normalizes
  // ---------- group k-1; one barrier per group ----------
  for (int k = 0; k <= 128; k++) {
    if (wv == 0) {
      if (k < 128) {
        const int tbeg = (k == 0) ? 1 : 16 * k;
        const int tend = 16 * k + 16;
        for (int t = tbeg; t < tend; t++) {
          const int ecur = etn;
          etn = seq_lds[(t + 1 < T_LEN) ? t + 1 : T_LEN - 1];   // LDS broadcast
          const float bt0 = Bt_lds[ecur * S + b0c];
          const float bt1 = Bt_lds[ecur * S + b1c];
          float x[MAXG];
#pragma unroll
          for (int e = 0; e < MAXG; e++) x[e] = alpha_lds[gsrc[e]];
          float aA = 0.f, aB = 0.f, bA = 0.f, bB = 0.f;
#pragma unroll
          for (int e = 0; e < MAXG; e += 2) {
            aA += x[e] * w0v[e];     aB += x[e + 1] * w0v[e + 1];
            bA += x[e] * w1v[e];     bB += x[e + 1] * w1v[e + 1];
          }
          u0 = (aA + aB) * bt0;
          u1 = (bA + bB) * bt1;
          const float sumv = x[0] + sm1 * x[1] + sm2 * x[2];

          u0 = (u0 >= FLUSH_EPS) ? u0 : 0.f;
          u1 = (u1 >= FLUSH_EPS) ? u1 : 0.f;

          if ((t & 15) == 15) {                  // last step of each group
            float m = fmaxf(u0, u1);
#pragma unroll
            for (int msk = 1; msk < 64; msk <<= 1) m = fmaxf(m, __shfl_xor(m, msk, 64));
            const float r = RESCALE_TARGET / m;
            u0 *= r; u1 *= r;
          }

          alpha_lds[d0] = u0;
          alpha_lds[d1] = u1;
          const int rs = (t & 31) * S;
          if (o0 >= 0) ring[rs + o0] = u0;       // LDS-only output staging
          if (o1 >= 0) ring[rs + o1] = u1;
          if (scol >= 0 && (t & 15) != 0) ring[((t - 1) & 31) * S + scol] = sumv;
        }
        if (scol >= 0) {  // end-of-group: split-col value for the group's last row
          const float x0 = alpha_lds[gsrc[0]];
          const float x1 = alpha_lds[gsrc[1]];
          const float x2 = alpha_lds[gsrc[2]];
          ring[((tend - 1) & 31) * S + scol] = x0 + sm1 * x1 + sm2 * x2;
        }
      }
    } else {
      if (k > 0) {  // drain + normalize group k-1 (other ring half)
        const int g = k - 1;
        const float* srcb = &ring[(g & 1) * 16 * S];
        float* dstb = ob + (size_t)g * 16 * S;
        // 16 row-sums (independent 6-shfl chains; compiler interleaves)
#pragma unroll
        for (int r = 0; r < 16; r++) {
          float sv = srcb[r * S + lid];
          if (lid + 64 < S) sv += srcb[r * S + lid + 64];
#pragma unroll
          for (int msk = 1; msk < 64; msk <<= 1) sv += __shfl_xor(sv, msk, 64);
          if (lid == 0) inv_lds[r] = 1.f / sv;
        }
        // normalize + coalesced float4 store (16*108 = 432 float4)
#pragma unroll
        for (int k2 = 0; k2 < 7; k2++) {
          const int i4 = k2 * 64 + lid;
          if (i4 < 27 * 16) {
            float4 v = ((const float4*)srcb)[i4];
            const float iv = inv_lds[i4 / 27];
            v.x *= iv; v.y *= iv; v.z *= iv; v.w *= iv;
            ((float4*)dstb)[i4] = v;
          }
        }
      }
    }
    __syncthreads();
  }
}

extern "C" void kernel_launch(void* const* d_in, const int* in_sizes, int n_in,
                              void* d_out, int out_size, void* d_ws, size_t ws_size,
                              hipStream_t stream) {
  const int* inp = (const int*)d_in[0];
  const float* w = (const float*)d_in[1];
  const float* ek = (const float*)d_in[2];
  const float* ik = (const float*)d_in[3];
  float* out = (float*)d_out;
  (void)d_ws; (void)ws_size; (void)in_sizes; (void)n_in; (void)out_size;
  hmm_scan_kernel<<<N_BATCH, 128, 0, stream>>>(inp, w, ek, ik, out);
}

// Round 13
// 552.150 us; speedup vs baseline: 1.1712x; 1.1577x over previous
//
#include <hip/hip_runtime.h>
#include <cstdint>
#include <cstddef>

#define S 108
#define NEMIT 126
#define T_LEN 2048
#define N_BATCH 256
#define MAXG 12    // max gather entries per lane after balancing
#define MAXNE 6500 // emission nnz upper bound (actual 6432)
#define NE_A 280   // A-matrix nnz

#define RESCALE_TARGET 1e24f
#define FLUSH_EPS 1e-30f

// ================= compile-time emission structure =================
struct EmTab {
  short row[MAXNE];
  short col[MAXNE];
  short widx[MAXNE];
  int rp[S + 1];
  int n;
  int nw;
};

constexpr int cmask(int sym, int add4) {
  int m = (sym == 4) ? 0xF : (1 << sym);
  if (add4) m |= 0x10;
  return m;
}

constexpr EmTab buildEm() {
  EmTab E{};
  int n = 0, k = 0;
  auto doCall = [&](int stt, int s0_, int s1_, int s2_, int xm_, int tr_) {
    const int m0 = cmask(s0_, xm_ < 2 ? 1 : 0);
    const int m1 = cmask(s1_, xm_ < 1 ? 1 : 0);
    const int m2 = cmask(s2_, 0);
    for (int x0 = 0; x0 < 5; x0++) {
      if (!((m0 >> x0) & 1)) continue;
      for (int x1 = 0; x1 < 5; x1++) {
        if (!((m1 >> x1) & 1)) continue;
        if (x0 != 4 && x1 == 4) continue;
        for (int x2 = 0; x2 < 5; x2++) {
          if (!((m2 >> x2) & 1)) continue;
          E.row[n] = (short)stt;
          E.col[n] = (short)(x0 * 25 + x1 * 5 + x2);
          E.widx[n] = (short)(tr_ ? k++ : -1);
          n++;
        }
      }
    }
  };
  doCall(0, 4, 4, 4, 0, 1);
  doCall(1, 4, 4, 0, 0, 1);
  doCall(2, 4, 0, 3, 0, 1);
  doCall(3, 0, 3, 2, 2, 0);
  doCall(4, 3, 2, 4, 2, 1);
  doCall(5, 2, 4, 4, 2, 1);
  for (int s = 6; s <= 51; s++) doCall(s, 4, 4, 4, 2, 1);
  doCall(52, 4, 4, 3, 2, 1);
  doCall(53, 4, 3, 0, 2, 1);
  doCall(53, 4, 3, 2, 2, 1);
  doCall(54, 3, 0, 0, 2, 0);
  doCall(54, 3, 0, 2, 2, 0);
  doCall(54, 3, 2, 0, 2, 0);
  doCall(55, 4, 4, 4, 2, 1);
  for (int s = 56; s <= 106; s++) doCall(s, 4, 4, 4, 2, 1);
  E.row[n] = 107; E.col[n] = 125; E.widx[n] = -1; n++;
  E.n = n; E.nw = k;
  for (int r = 0; r <= S; r++) E.rp[r] = 0;
  for (int e = 0; e < n; e++) E.rp[E.row[e] + 1]++;
  for (int r = 0; r < S; r++) E.rp[r + 1] += E.rp[r];
  return E;
}

constexpr EmTab EM_HOST = buildEm();
static_assert(EM_HOST.n <= MAXNE && EM_HOST.n > 6000, "emission count sanity");
__device__ const EmTab g_em = EM_HOST;

// ================= compile-time A structure + full gather plan =================
struct APlan {
  short vcode[NE_A], vwi[NE_A];
  short aidx[NE_A];
  short arp[S + 1];
  unsigned char src[64][MAXG];
  short a0[64][MAXG], a1[64][MAXG];
  unsigned char d0[64], d1[64], b0[64], b1[64];
  short o0[64], o1[64], scol[64];
  unsigned char sm1[64], sm2[64];
  int maxload, ncons, np;
};

constexpr APlan buildPlan() {
  APlan P{};
  short arow[NE_A] = {}, acol[NE_A] = {};
  int ne = 0;
  auto AD = [&](int r, int c, int code, int wi) {
    arow[ne] = (short)r; acol[ne] = (short)c;
    P.vcode[ne] = (short)code; P.vwi[ne] = (short)wi; ne++;
  };
  AD(0, 0, 2, 0); AD(0, 1, 1, 0); AD(1, 2, 0, 0); AD(2, 3, 0, 0);
  for (int i = 0; i < 16; i++) AD(3 + 3 * i, 4 + 3 * i, 1, 1 + i);
  for (int i = 0; i < 16; i++) AD(4 + 3 * i, 5 + 3 * i, 0, 0);
  for (int i = 0; i < 16; i++) AD(5 + 3 * i, 6 + 3 * i, 0, 0);
  for (int i = 0; i <= 16; i++) AD(3 + 3 * i, 56 + 3 * i, 1, 17 + i);
  AD(51, 52, 1, 34);
  for (int i = 0; i <= 16; i++) AD(56 + 3 * i, 57 + 3 * i, 0, 0);
  for (int i = 0; i <= 16; i++) AD(57 + 3 * i, 58 + 3 * i, 0, 0);
  for (int i = 0; i <= 16; i++) AD(58 + 3 * i, 4 + 3 * i, 1, 35 + i);
  for (int i = 0; i <= 16; i++) AD(58 + 3 * i, 56 + 3 * i, 2, 35 + i);
  for (int a = 0; a < 16; a++)
    for (int jj = a + 1; jj <= 16; jj++) AD(3 + 3 * a, 4 + 3 * jj, 3, jj - a + 1);
  AD(52, 53, 0, 0); AD(53, 54, 0, 0); AD(54, 55, 0, 0);
  AD(55, 55, 0, 0); AD(55, 107, 0, 0); AD(107, 107, 0, 0);

  int rc[S + 1] = {};
  for (int e = 0; e < ne; e++) rc[arow[e] + 1]++;
  for (int r = 0; r < S; r++) rc[r + 1] += rc[r];
  for (int r = 0; r <= S; r++) P.arp[r] = (short)rc[r];
  int fill[S] = {};
  for (int e = 0; e < ne; e++) { const int r = arow[e]; P.aidx[rc[r] + fill[r]] = (short)e; fill[r]++; }

  int ccnt[S] = {}; short clist[S][18] = {};
  for (int e = 0; e < ne; e++) { const int c = acol[e]; clist[c][ccnt[c]] = (short)e; ccnt[c]++; }
  int npcA[S] = {};
  short pdefs[16][6] = {}; int pcnt[16] = {}; short pcol[16] = {};
  int np = 0;
  for (int c = 0; c < S; c++) {
    while (ccnt[c] > 8) {
      const int base = ccnt[c] - 6;
      for (int j = 0; j < 6; j++) pdefs[np][j] = clist[c][base + j];
      pcnt[np] = 6; pcol[np] = (short)c;
      npcA[c]++; ccnt[c] -= 6; np++;
    }
  }
  int lload[64] = {}, lnit[64] = {};
  for (int l = 0; l < 64; l++) {
    for (int e = 0; e < MAXG; e++) { P.src[l][e] = 0; P.a0[l][e] = -1; P.a1[l][e] = -1; }
    P.d0[l] = 127; P.d1[l] = 127; P.b0[l] = 0; P.b1[l] = 0;
    P.o0[l] = -1; P.o1[l] = -1; P.scol[l] = -1; P.sm1[l] = 0; P.sm2[l] = 0;
  }
  int ncons = 0;
  for (int c = 0; c < S; c++) {
    if (ccnt[c] == 1) {
      const int e0 = clist[c][0];
      const int r = arow[e0];
      if (npcA[r] > 0) {
        const int l = 54 + ncons; ncons++;
        int k = 0;
        P.src[l][k] = (unsigned char)r; P.a0[l][k] = (short)e0; k++;
        for (int p = 0; p < np; p++)
          if (pcol[p] == r) { P.src[l][k] = (unsigned char)(108 + p); P.a0[l][k] = (short)e0; k++; }
        P.d0[l] = (unsigned char)c; P.b0[l] = (unsigned char)c; P.o0[l] = (short)c;
        P.scol[l] = (short)r;
        P.sm1[l] = (k >= 2) ? 1 : 0; P.sm2[l] = (k >= 3) ? 1 : 0;
        lload[l] = k; lnit[l] = 1;
        ccnt[c] = 0;
      }
    }
  }
  int rr = 0;
  auto pickLane = [&](int L) {
    for (;;) {
      const int pos = rr & 127; rr++;
      const int l = (pos < 64) ? pos : (127 - pos);
      if (lnit[l] < 2 && lload[l] + L <= MAXG) return l;
    }
  };
  for (int th = 8; th >= 1; th--) {
    for (int p = 0; p < np; p++) {
      if (pcnt[p] != th) continue;
      const int l = pickLane(th);
      const int it = lnit[l], base = lload[l];
      for (int j = 0; j < th; j++) {
        P.src[l][base + j] = (unsigned char)arow[pdefs[p][j]];
        if (it == 0) P.a0[l][base + j] = pdefs[p][j];
        else         P.a1[l][base + j] = pdefs[p][j];
      }
      if (it == 0) { P.d0[l] = (unsigned char)(108 + p); P.b0[l] = (unsigned char)pcol[p]; P.o0[l] = -1; }
      else         { P.d1[l] = (unsigned char)(108 + p); P.b1[l] = (unsigned char)pcol[p]; P.o1[l] = -1; }
      lload[l] = base + th; lnit[l] = it + 1;
    }
    for (int c = 0; c < S; c++) {
      if (ccnt[c] != th) continue;
      const int l = pickLane(th);
      const int it = lnit[l], base = lload[l];
      for (int j = 0; j < th; j++) {
        P.src[l][base + j] = (unsigned char)arow[clist[c][j]];
        if (it == 0) P.a0[l][base + j] = clist[c][j];
        else         P.a1[l][base + j] = clist[c][j];
      }
      const short oc = (npcA[c] > 0) ? (short)-1 : (short)c;
      if (it == 0) { P.d0[l] = (unsigned char)c; P.b0[l] = (unsigned char)c; P.o0[l] = oc; }
      else         { P.d1[l] = (unsigned char)c; P.b1[l] = (unsigned char)c; P.o1[l] = oc; }
      lload[l] = base + th; lnit[l] = it + 1;
    }
  }
  int ml = 0;
  for (int l = 0; l < 64; l++) ml = (lload[l] > ml) ? lload[l] : ml;
  P.maxload = ml; P.ncons = ncons; P.np = np;
  return P;
}

constexpr APlan PLAN_HOST = buildPlan();
static_assert(PLAN_HOST.maxload <= MAXG, "lane gather overflow");
static_assert(PLAN_HOST.ncons <= 10, "too many consumer lanes");
static_assert(PLAN_HOST.np <= 16, "too many pieces");
__device__ const APlan g_plan = PLAN_HOST;

// ================= scan kernel: R10 producer + light normalizing consumer ======
__global__ __launch_bounds__(128, 1) void hmm_scan_kernel(
    const int* __restrict__ inp, const float* __restrict__ w,
    const float* __restrict__ ek, const float* __restrict__ ik,
    float* __restrict__ out) {
  __shared__ __align__(16) float Bt_lds[NEMIT * S];
  __shared__ __align__(16) float ring[32 * S];   // 32-row output ring (2 halves)
  __shared__ float alpha_lds[128];               // 108 states + piece slots + trash
  __shared__ float pi_lds[S];
  __shared__ float avalS[NE_A];
  __shared__ __align__(16) int seq_lds[T_LEN];   // whole symbol sequence (8 KB)

  const int tid = threadIdx.x;
  const int lid = tid & 63;
  const int wv = tid >> 6;   // 0 = producer, 1 = consumer

  // ---------- setup (both waves cooperate) ----------
  for (int i = tid; i < NEMIT * S; i += 128) Bt_lds[i] = 0.f;

  {  // seq -> LDS (int4 loads)
    const int4* s4 = (const int4*)(inp + (size_t)blockIdx.x * T_LEN);
    int4* d4 = (int4*)seq_lds;
    for (int i = tid; i < T_LEN / 4; i += 128) d4[i] = s4[i];
  }

  if (wv == 0) {  // pi = softmax(ik), single wave (shfl)
    float q0 = ik[lid];
    float q1 = (lid + 64 < S) ? ik[lid + 64] : -1e30f;
    float mx = fmaxf(q0, q1);
#pragma unroll
    for (int msk = 1; msk < 64; msk <<= 1) mx = fmaxf(mx, __shfl_xor(mx, msk, 64));
    float e0v = expf(q0 - mx);
    float e1v = (lid + 64 < S) ? expf(q1 - mx) : 0.f;
    float zz = e0v + e1v;
#pragma unroll
    for (int msk = 1; msk < 64; msk <<= 1) zz += __shfl_xor(zz, msk, 64);
    const float rz = 1.f / zz;
    pi_lds[lid] = e0v * rz;
    if (lid + 64 < S) pi_lds[lid + 64] = e1v * rz;
  }

  {  // A values from descriptors, parallel across 128 threads
    const float wk = w[52];
    const float aw = fabsf(wk);
    const float sgnw = (wk > 0.f) ? 1.f : ((wk < 0.f) ? -1.f : 0.f);
    for (int e = tid; e < NE_A; e += 128) {
      const int code = g_plan.vcode[e];
      const int wi = g_plan.vwi[e];
      float v;
      if (code == 0) v = 1.f;
      else if (code == 1) v = w[wi];
      else if (code == 2) v = 1.f - w[wi];
      else {
        const float pw = powf(aw, (float)wi);
        v = 1.f - ((wi & 1) ? sgnw : 1.f) * pw;
      }
      avalS[e] = v;
    }
  }
  __syncthreads();

  // A row-softmax (one row per thread, 108 < 128)
  if (tid < S) {
    const int b = g_plan.arp[tid], e2 = g_plan.arp[tid + 1];
    float m = -1e30f;
    for (int j = b; j < e2; j++) m = fmaxf(m, avalS[g_plan.aidx[j]]);
    float z = 0.f;
    for (int j = b; j < e2; j++) z += expf(avalS[g_plan.aidx[j]] - m);
    const float rz = 1.f / z;
    for (int j = b; j < e2; j++) {
      const int ii = g_plan.aidx[j];
      avalS[ii] = expf(avalS[ii] - m) * rz;
    }
  }
  __syncthreads();

  // B row-softmax (one row per thread)
  if (tid < S) {
    const int r = tid;
    const int b = g_em.rp[r], e2 = g_em.rp[r + 1];
    float m = -1e30f;
    for (int e = b; e < e2; e++) {
      const int wi = g_em.widx[e];
      m = fmaxf(m, (wi >= 0) ? ek[wi] : 1.f);
    }
    float z = 0.f;
    for (int e = b; e < e2; e++) {
      const int wi = g_em.widx[e];
      z += expf(((wi >= 0) ? ek[wi] : 1.f) - m);
    }
    const float rz = 1.f / z;
    for (int e = b; e < e2; e++) {
      const int wi = g_em.widx[e];
      Bt_lds[(int)g_em.col[e] * S + r] = expf(((wi >= 0) ? ek[wi] : 1.f) - m) * rz;
    }
  }

  // plan -> registers (indexed by lane; wave 1 loads too, unused)
  int gsrc[MAXG]; float w0v[MAXG], w1v[MAXG];
#pragma unroll
  for (int e = 0; e < MAXG; e++) {
    gsrc[e] = g_plan.src[lid][e];
    const int a0 = g_plan.a0[lid][e], a1 = g_plan.a1[lid][e];
    w0v[e] = (a0 >= 0) ? avalS[a0] : 0.f;
    w1v[e] = (a1 >= 0) ? avalS[a1] : 0.f;
  }
  const int d0 = g_plan.d0[lid], d1 = g_plan.d1[lid];
  const int b0c = g_plan.b0[lid], b1c = g_plan.b1[lid];
  const int o0 = g_plan.o0[lid], o1 = g_plan.o1[lid];
  const int scol = g_plan.scol[lid];
  const float sm1 = (float)g_plan.sm1[lid], sm2 = (float)g_plan.sm2[lid];
  __syncthreads();   // Bt_lds, avalS, seq_lds final

  float* ob = out + (size_t)blockIdx.x * T_LEN * S;
  int etn = 0;
  float u0 = 0.f, u1 = 0.f;

  if (wv == 0) {  // init: row 0 into alpha + ring row 0
    const int e0s = seq_lds[0];
    const float ui0 = (d0 < 108) ? RESCALE_TARGET * pi_lds[d0] * Bt_lds[e0s * S + d0] : 0.f;
    const float ui1 = (d1 < 108) ? RESCALE_TARGET * pi_lds[d1] * Bt_lds[e0s * S + d1] : 0.f;
    alpha_lds[d0] = ui0;
    alpha_lds[d1] = ui1;
    for (int i = lid; i < S; i += 64) ring[i] = alpha_lds[i];   // same-wave order OK
    etn = seq_lds[1];
  }

  // ---------- main: producer fills group k (k<128); consumer drains+normalizes
  // ---------- group k-1; one barrier per group ----------
  for (int k = 0; k <= 128; k++) {
    if (wv == 0) {
      if (k < 128) {
        const int tbeg = (k == 0) ? 1 : 16 * k;
        const int tend = 16 * k + 16;
        for (int t = tbeg; t < tend; t++) {
          const int ecur = etn;
          etn = seq_lds[(t + 1 < T_LEN) ? t + 1 : T_LEN - 1];   // LDS broadcast
          const float bt0 = Bt_lds[ecur * S + b0c];
          const float bt1 = Bt_lds[ecur * S + b1c];
          float x[MAXG];
#pragma unroll
          for (int e = 0; e < MAXG; e++) x[e] = alpha_lds[gsrc[e]];
          float aA = 0.f, aB = 0.f, bA = 0.f, bB = 0.f;
#pragma unroll
          for (int e = 0; e < MAXG; e += 2) {
            aA += x[e] * w0v[e];     aB += x[e + 1] * w0v[e + 1];
            bA += x[e] * w1v[e];     bB += x[e + 1] * w1v[e + 1];
          }
          u0 = (aA + aB) * bt0;
          u1 = (bA + bB) * bt1;
          const float sumv = x[0] + sm1 * x[1] + sm2 * x[2];

          u0 = (u0 >= FLUSH_EPS) ? u0 : 0.f;
          u1 = (u1 >= FLUSH_EPS) ? u1 : 0.f;

          if ((t & 15) == 15) {                  // last step of each group
            float m = fmaxf(u0, u1);
#pragma unroll
            for (int msk = 1; msk < 64; msk <<= 1) m = fmaxf(m, __shfl_xor(m, msk, 64));
            const float r = RESCALE_TARGET / m;
            u0 *= r; u1 *= r;
          }

          alpha_lds[d0] = u0;
          alpha_lds[d1] = u1;
          const int rs = (t & 31) * S;
          if (o0 >= 0) ring[rs + o0] = u0;       // LDS-only output staging
          if (o1 >= 0) ring[rs + o1] = u1;
          if (scol >= 0 && (t & 15) != 0) ring[((t - 1) & 31) * S + scol] = sumv;
        }
        if (scol >= 0) {  // end-of-group: split-col value for the group's last row
          const float x0 = alpha_lds[gsrc[0]];
          const float x1 = alpha_lds[gsrc[1]];
          const float x2 = alpha_lds[gsrc[2]];
          ring[((tend - 1) & 31) * S + scol] = x0 + sm1 * x1 + sm2 * x2;
        }
      }
    } else {
      if (k > 0) {  // drain + normalize group k-1 (other ring half)
        // 4 lanes per row: lanes 4r..4r+3 own row r (16 rows).
        // Each lane reads its <=7 float4s ONCE into registers, partial-sums,
        // 2-level shfl within the 4-lane group -> row sum in all 4 lanes,
        // then scales the registers and stores. 7 reads + 2 shfl + 7 stores.
        const int g = k - 1;
        const float4* srcb4 = (const float4*)&ring[(g & 1) * 16 * S];
        float4* dstb4 = (float4*)(ob + (size_t)g * 16 * S);
        const int r = lid >> 2;   // row 0..15
        const int j = lid & 3;    // sub-lane within row group
        float4 v0, v1, v2, v3, v4, v5, v6;
        float psum = 0.f;
        v6 = make_float4(0.f, 0.f, 0.f, 0.f);
        const int base4 = r * 27 + j;
        v0 = srcb4[base4];
        v1 = srcb4[base4 + 4];
        v2 = srcb4[base4 + 8];
        v3 = srcb4[base4 + 12];
        v4 = srcb4[base4 + 16];
        v5 = srcb4[base4 + 20];
        if (j < 3) v6 = srcb4[base4 + 24];   // col 24..26 only (27 float4/row)
        psum = v0.x + v0.y + v0.z + v0.w + v1.x + v1.y + v1.z + v1.w
             + v2.x + v2.y + v2.z + v2.w + v3.x + v3.y + v3.z + v3.w
             + v4.x + v4.y + v4.z + v4.w + v5.x + v5.y + v5.z + v5.w
             + v6.x + v6.y + v6.z + v6.w;
        psum += __shfl_xor(psum, 1, 64);
        psum += __shfl_xor(psum, 2, 64);
        const float iv = 1.f / psum;
        v0.x *= iv; v0.y *= iv; v0.z *= iv; v0.w *= iv;
        v1.x *= iv; v1.y *= iv; v1.z *= iv; v1.w *= iv;
        v2.x *= iv; v2.y *= iv; v2.z *= iv; v2.w *= iv;
        v3.x *= iv; v3.y *= iv; v3.z *= iv; v3.w *= iv;
        v4.x *= iv; v4.y *= iv; v4.z *= iv; v4.w *= iv;
        v5.x *= iv; v5.y *= iv; v5.z *= iv; v5.w *= iv;
        v6.x *= iv; v6.y *= iv; v6.z *= iv; v6.w *= iv;
        dstb4[base4] = v0;
        dstb4[base4 + 4] = v1;
        dstb4[base4 + 8] = v2;
        dstb4[base4 + 12] = v3;
        dstb4[base4 + 16] = v4;
        dstb4[base4 + 20] = v5;
        if (j < 3) dstb4[base4 + 24] = v6;
      }
    }
    __syncthreads();
  }
}

extern "C" void kernel_launch(void* const* d_in, const int* in_sizes, int n_in,
                              void* d_out, int out_size, void* d_ws, size_t ws_size,
                              hipStream_t stream) {
  const int* inp = (const int*)d_in[0];
  const float* w = (const float*)d_in[1];
  const float* ek = (const float*)d_in[2];
  const float* ik = (const float*)d_in[3];
  float* out = (float*)d_out;
  (void)d_ws; (void)ws_size; (void)in_sizes; (void)n_in; (void)out_size;
  hmm_scan_kernel<<<N_BATCH, 128, 0, stream>>>(inp, w, ek, ik, out);
}

// Round 14
// 413.345 us; speedup vs baseline: 1.5644x; 1.3358x over previous
//
#include <hip/hip_runtime.h>
#include <cstdint>
#include <cstddef>

#define S 108
#define NEMIT 126
#define T_LEN 2048
#define N_BATCH 256
#define MAXG 10    // max gather entries per lane after balancing (tightened)
#define MAXNE 6500 // emission nnz upper bound (actual 6432)
#define NE_A 280   // A-matrix nnz
#define TRASH_IDX (32 * S)   // ring trash slot for masked-out lanes

#define RESCALE_TARGET 1e24f

// ================= compile-time emission structure =================
struct EmTab {
  short row[MAXNE];
  short col[MAXNE];
  short widx[MAXNE];
  int rp[S + 1];
  int n;
  int nw;
};

constexpr int cmask(int sym, int add4) {
  int m = (sym == 4) ? 0xF : (1 << sym);
  if (add4) m |= 0x10;
  return m;
}

constexpr EmTab buildEm() {
  EmTab E{};
  int n = 0, k = 0;
  auto doCall = [&](int stt, int s0_, int s1_, int s2_, int xm_, int tr_) {
    const int m0 = cmask(s0_, xm_ < 2 ? 1 : 0);
    const int m1 = cmask(s1_, xm_ < 1 ? 1 : 0);
    const int m2 = cmask(s2_, 0);
    for (int x0 = 0; x0 < 5; x0++) {
      if (!((m0 >> x0) & 1)) continue;
      for (int x1 = 0; x1 < 5; x1++) {
        if (!((m1 >> x1) & 1)) continue;
        if (x0 != 4 && x1 == 4) continue;
        for (int x2 = 0; x2 < 5; x2++) {
          if (!((m2 >> x2) & 1)) continue;
          E.row[n] = (short)stt;
          E.col[n] = (short)(x0 * 25 + x1 * 5 + x2);
          E.widx[n] = (short)(tr_ ? k++ : -1);
          n++;
        }
      }
    }
  };
  doCall(0, 4, 4, 4, 0, 1);
  doCall(1, 4, 4, 0, 0, 1);
  doCall(2, 4, 0, 3, 0, 1);
  doCall(3, 0, 3, 2, 2, 0);
  doCall(4, 3, 2, 4, 2, 1);
  doCall(5, 2, 4, 4, 2, 1);
  for (int s = 6; s <= 51; s++) doCall(s, 4, 4, 4, 2, 1);
  doCall(52, 4, 4, 3, 2, 1);
  doCall(53, 4, 3, 0, 2, 1);
  doCall(53, 4, 3, 2, 2, 1);
  doCall(54, 3, 0, 0, 2, 0);
  doCall(54, 3, 0, 2, 2, 0);
  doCall(54, 3, 2, 0, 2, 0);
  doCall(55, 4, 4, 4, 2, 1);
  for (int s = 56; s <= 106; s++) doCall(s, 4, 4, 4, 2, 1);
  E.row[n] = 107; E.col[n] = 125; E.widx[n] = -1; n++;
  E.n = n; E.nw = k;
  for (int r = 0; r <= S; r++) E.rp[r] = 0;
  for (int e = 0; e < n; e++) E.rp[E.row[e] + 1]++;
  for (int r = 0; r < S; r++) E.rp[r + 1] += E.rp[r];
  return E;
}

constexpr EmTab EM_HOST = buildEm();
static_assert(EM_HOST.n <= MAXNE && EM_HOST.n > 6000, "emission count sanity");
__device__ const EmTab g_em = EM_HOST;

// ================= compile-time A structure + full gather plan =================
struct APlan {
  short vcode[NE_A], vwi[NE_A];
  short aidx[NE_A];
  short arp[S + 1];
  unsigned char src[64][MAXG];
  short a0[64][MAXG], a1[64][MAXG];
  unsigned char d0[64], d1[64], b0[64], b1[64];
  short o0[64], o1[64], scol[64];
  unsigned char sm1[64], sm2[64];
  int maxload, ncons, np;
};

constexpr APlan buildPlan() {
  APlan P{};
  short arow[NE_A] = {}, acol[NE_A] = {};
  int ne = 0;
  auto AD = [&](int r, int c, int code, int wi) {
    arow[ne] = (short)r; acol[ne] = (short)c;
    P.vcode[ne] = (short)code; P.vwi[ne] = (short)wi; ne++;
  };
  AD(0, 0, 2, 0); AD(0, 1, 1, 0); AD(1, 2, 0, 0); AD(2, 3, 0, 0);
  for (int i = 0; i < 16; i++) AD(3 + 3 * i, 4 + 3 * i, 1, 1 + i);
  for (int i = 0; i < 16; i++) AD(4 + 3 * i, 5 + 3 * i, 0, 0);
  for (int i = 0; i < 16; i++) AD(5 + 3 * i, 6 + 3 * i, 0, 0);
  for (int i = 0; i <= 16; i++) AD(3 + 3 * i, 56 + 3 * i, 1, 17 + i);
  AD(51, 52, 1, 34);
  for (int i = 0; i <= 16; i++) AD(56 + 3 * i, 57 + 3 * i, 0, 0);
  for (int i = 0; i <= 16; i++) AD(57 + 3 * i, 58 + 3 * i, 0, 0);
  for (int i = 0; i <= 16; i++) AD(58 + 3 * i, 4 + 3 * i, 1, 35 + i);
  for (int i = 0; i <= 16; i++) AD(58 + 3 * i, 56 + 3 * i, 2, 35 + i);
  for (int a = 0; a < 16; a++)
    for (int jj = a + 1; jj <= 16; jj++) AD(3 + 3 * a, 4 + 3 * jj, 3, jj - a + 1);
  AD(52, 53, 0, 0); AD(53, 54, 0, 0); AD(54, 55, 0, 0);
  AD(55, 55, 0, 0); AD(55, 107, 0, 0); AD(107, 107, 0, 0);

  int rc[S + 1] = {};
  for (int e = 0; e < ne; e++) rc[arow[e] + 1]++;
  for (int r = 0; r < S; r++) rc[r + 1] += rc[r];
  for (int r = 0; r <= S; r++) P.arp[r] = (short)rc[r];
  int fill[S] = {};
  for (int e = 0; e < ne; e++) { const int r = arow[e]; P.aidx[rc[r] + fill[r]] = (short)e; fill[r]++; }

  int ccnt[S] = {}; short clist[S][18] = {};
  for (int e = 0; e < ne; e++) { const int c = acol[e]; clist[c][ccnt[c]] = (short)e; ccnt[c]++; }
  int npcA[S] = {};
  short pdefs[16][6] = {}; int pcnt[16] = {}; short pcol[16] = {};
  int np = 0;
  for (int c = 0; c < S; c++) {
    while (ccnt[c] > 8) {
      const int base = ccnt[c] - 6;
      for (int j = 0; j < 6; j++) pdefs[np][j] = clist[c][base + j];
      pcnt[np] = 6; pcol[np] = (short)c;
      npcA[c]++; ccnt[c] -= 6; np++;
    }
  }
  int lload[64] = {}, lnit[64] = {};
  for (int l = 0; l < 64; l++) {
    for (int e = 0; e < MAXG; e++) { P.src[l][e] = 0; P.a0[l][e] = -1; P.a1[l][e] = -1; }
    P.d0[l] = 127; P.d1[l] = 127; P.b0[l] = 0; P.b1[l] = 0;
    P.o0[l] = -1; P.o1[l] = -1; P.scol[l] = -1; P.sm1[l] = 0; P.sm2[l] = 0;
  }
  int ncons = 0;
  for (int c = 0; c < S; c++) {
    if (ccnt[c] == 1) {
      const int e0 = clist[c][0];
      const int r = arow[e0];
      if (npcA[r] > 0) {
        const int l = 54 + ncons; ncons++;
        int k = 0;
        P.src[l][k] = (unsigned char)r; P.a0[l][k] = (short)e0; k++;
        for (int p = 0; p < np; p++)
          if (pcol[p] == r) { P.src[l][k] = (unsigned char)(108 + p); P.a0[l][k] = (short)e0; k++; }
        P.d0[l] = (unsigned char)c; P.b0[l] = (unsigned char)c; P.o0[l] = (short)c;
        P.scol[l] = (short)r;
        P.sm1[l] = (k >= 2) ? 1 : 0; P.sm2[l] = (k >= 3) ? 1 : 0;
        lload[l] = k; lnit[l] = 1;
        ccnt[c] = 0;
      }
    }
  }
  int rr = 0;
  auto pickLane = [&](int L) {
    for (;;) {
      const int pos = rr & 127; rr++;
      const int l = (pos < 64) ? pos : (127 - pos);
      if (lnit[l] < 2 && lload[l] + L <= MAXG) return l;
    }
  };
  for (int th = 8; th >= 1; th--) {
    for (int p = 0; p < np; p++) {
      if (pcnt[p] != th) continue;
      const int l = pickLane(th);
      const int it = lnit[l], base = lload[l];
      for (int j = 0; j < th; j++) {
        P.src[l][base + j] = (unsigned char)arow[pdefs[p][j]];
        if (it == 0) P.a0[l][base + j] = pdefs[p][j];
        else         P.a1[l][base + j] = pdefs[p][j];
      }
      if (it == 0) { P.d0[l] = (unsigned char)(108 + p); P.b0[l] = (unsigned char)pcol[p]; P.o0[l] = -1; }
      else         { P.d1[l] = (unsigned char)(108 + p); P.b1[l] = (unsigned char)pcol[p]; P.o1[l] = -1; }
      lload[l] = base + th; lnit[l] = it + 1;
    }
    for (int c = 0; c < S; c++) {
      if (ccnt[c] != th) continue;
      const int l = pickLane(th);
      const int it = lnit[l], base = lload[l];
      for (int j = 0; j < th; j++) {
        P.src[l][base + j] = (unsigned char)arow[clist[c][j]];
        if (it == 0) P.a0[l][base + j] = clist[c][j];
        else         P.a1[l][base + j] = clist[c][j];
      }
      const short oc = (npcA[c] > 0) ? (short)-1 : (short)c;
      if (it == 0) { P.d0[l] = (unsigned char)c; P.b0[l] = (unsigned char)c; P.o0[l] = oc; }
      else         { P.d1[l] = (unsigned char)c; P.b1[l] = (unsigned char)c; P.o1[l] = oc; }
      lload[l] = base + th; lnit[l] = it + 1;
    }
  }
  int ml = 0;
  for (int l = 0; l < 64; l++) ml = (lload[l] > ml) ? lload[l] : ml;
  P.maxload = ml; P.ncons = ncons; P.np = np;
  return P;
}

constexpr APlan PLAN_HOST = buildPlan();
static_assert(PLAN_HOST.maxload <= MAXG, "lane gather overflow");
static_assert(PLAN_HOST.ncons <= 10, "too many consumer lanes");
static_assert(PLAN_HOST.np <= 16, "too many pieces");
__device__ const APlan g_plan = PLAN_HOST;

// One producer step. SYM_: symbol. RS_: ring offset of row t (row*S).
// PRS_: ring offset of row t-1. RESC_: rescale (compile-time). SCOK_: emit
// the split-col write for row t-1 (compile-time). Gathers issue FIRST; masked
// writes are unconditional ds_writes with cndmask'd trash address.
#define PSTEP(SYM_, RS_, PRS_, RESC_, SCOK_)                              \
  {                                                                       \
    const int ecur_ = (SYM_);                                             \
    float x[MAXG];                                                        \
    _Pragma("unroll")                                                     \
    for (int e = 0; e < MAXG; e++) x[e] = alpha_lds[gsrc[e]];             \
    const float bt0_ = Bt_lds[ecur_ * S + b0c];                           \
    const float bt1_ = Bt_lds[ecur_ * S + b1c];                           \
    float aA_ = 0.f, aB_ = 0.f, bA_ = 0.f, bB_ = 0.f;                     \
    _Pragma("unroll")                                                     \
    for (int e = 0; e < MAXG; e += 2) {                                   \
      aA_ += x[e] * w0v[e];     aB_ += x[e + 1] * w0v[e + 1];             \
      bA_ += x[e] * w1v[e];     bB_ += x[e + 1] * w1v[e + 1];             \
    }                                                                     \
    u0 = (aA_ + aB_) * bt0_;                                              \
    u1 = (bA_ + bB_) * bt1_;                                              \
    const float sumv_ = x[0] + sm1 * x[1] + sm2 * x[2];                   \
    if (RESC_) {                                                          \
      float m_ = fmaxf(u0, u1);                                           \
      _Pragma("unroll")                                                   \
      for (int msk_ = 1; msk_ < 64; msk_ <<= 1)                           \
        m_ = fmaxf(m_, __shfl_xor(m_, msk_, 64));                         \
      const float r_ = RESCALE_TARGET / m_;                               \
      u0 *= r_; u1 *= r_;                                                 \
    }                                                                     \
    alpha_lds[d0] = u0;                                                   \
    alpha_lds[d1] = u1;                                                   \
    const int a0_ = (o0 >= 0) ? (RS_) + o0 : TRASH_IDX;                   \
    const int a1_ = (o1 >= 0) ? (RS_) + o1 : TRASH_IDX;                   \
    ring[a0_] = u0;                                                       \
    ring[a1_] = u1;                                                       \
    if (SCOK_) {                                                          \
      const int a2_ = (scol >= 0) ? (PRS_) + scol : TRASH_IDX;            \
      ring[a2_] = sumv_;                                                  \
    }                                                                     \
  }

// ================= scan kernel: lean producer + light normalizing consumer =====
__global__ __launch_bounds__(128, 1) void hmm_scan_kernel(
    const int* __restrict__ inp, const float* __restrict__ w,
    const float* __restrict__ ek, const float* __restrict__ ik,
    float* __restrict__ out) {
  __shared__ __align__(16) float Bt_lds[NEMIT * S];
  __shared__ __align__(16) float ring[32 * S + 4];   // +trash slot at 32*S
  __shared__ float alpha_lds[128];
  __shared__ float pi_lds[S];
  __shared__ float avalS[NE_A];
  __shared__ __align__(16) int seq_lds[T_LEN + 16];  // padded: no bounds select

  const int tid = threadIdx.x;
  const int lid = tid & 63;
  const int wv = tid >> 6;   // 0 = producer, 1 = consumer

  // ---------- setup (both waves cooperate) ----------
  for (int i = tid; i < NEMIT * S; i += 128) Bt_lds[i] = 0.f;

  {  // seq -> LDS (int4 loads); pad with copies of last block
    const int4* s4 = (const int4*)(inp + (size_t)blockIdx.x * T_LEN);
    int4* d4 = (int4*)seq_lds;
    for (int i = tid; i < T_LEN / 4; i += 128) d4[i] = s4[i];
    if (tid < 4) d4[T_LEN / 4 + tid] = s4[T_LEN / 4 - 1];   // pad rows
  }

  if (wv == 0) {  // pi = softmax(ik), single wave (shfl)
    float q0 = ik[lid];
    float q1 = (lid + 64 < S) ? ik[lid + 64] : -1e30f;
    float mx = fmaxf(q0, q1);
#pragma unroll
    for (int msk = 1; msk < 64; msk <<= 1) mx = fmaxf(mx, __shfl_xor(mx, msk, 64));
    float e0v = expf(q0 - mx);
    float e1v = (lid + 64 < S) ? expf(q1 - mx) : 0.f;
    float zz = e0v + e1v;
#pragma unroll
    for (int msk = 1; msk < 64; msk <<= 1) zz += __shfl_xor(zz, msk, 64);
    const float rz = 1.f / zz;
    pi_lds[lid] = e0v * rz;
    if (lid + 64 < S) pi_lds[lid + 64] = e1v * rz;
  }

  {  // A values from descriptors, parallel across 128 threads
    const float wk = w[52];
    const float aw = fabsf(wk);
    const float sgnw = (wk > 0.f) ? 1.f : ((wk < 0.f) ? -1.f : 0.f);
    for (int e = tid; e < NE_A; e += 128) {
      const int code = g_plan.vcode[e];
      const int wi = g_plan.vwi[e];
      float v;
      if (code == 0) v = 1.f;
      else if (code == 1) v = w[wi];
      else if (code == 2) v = 1.f - w[wi];
      else {
        const float pw = powf(aw, (float)wi);
        v = 1.f - ((wi & 1) ? sgnw : 1.f) * pw;
      }
      avalS[e] = v;
    }
  }
  __syncthreads();

  // A row-softmax (one row per thread, 108 < 128)
  if (tid < S) {
    const int b = g_plan.arp[tid], e2 = g_plan.arp[tid + 1];
    float m = -1e30f;
    for (int j = b; j < e2; j++) m = fmaxf(m, avalS[g_plan.aidx[j]]);
    float z = 0.f;
    for (int j = b; j < e2; j++) z += expf(avalS[g_plan.aidx[j]] - m);
    const float rz = 1.f / z;
    for (int j = b; j < e2; j++) {
      const int ii = g_plan.aidx[j];
      avalS[ii] = expf(avalS[ii] - m) * rz;
    }
  }
  __syncthreads();

  // B row-softmax (one row per thread)
  if (tid < S) {
    const int r = tid;
    const int b = g_em.rp[r], e2 = g_em.rp[r + 1];
    float m = -1e30f;
    for (int e = b; e < e2; e++) {
      const int wi = g_em.widx[e];
      m = fmaxf(m, (wi >= 0) ? ek[wi] : 1.f);
    }
    float z = 0.f;
    for (int e = b; e < e2; e++) {
      const int wi = g_em.widx[e];
      z += expf(((wi >= 0) ? ek[wi] : 1.f) - m);
    }
    const float rz = 1.f / z;
    for (int e = b; e < e2; e++) {
      const int wi = g_em.widx[e];
      Bt_lds[(int)g_em.col[e] * S + r] = expf(((wi >= 0) ? ek[wi] : 1.f) - m) * rz;
    }
  }

  // plan -> registers (indexed by lane; wave 1 loads too, unused)
  int gsrc[MAXG]; float w0v[MAXG], w1v[MAXG];
#pragma unroll
  for (int e = 0; e < MAXG; e++) {
    gsrc[e] = g_plan.src[lid][e];
    const int a0 = g_plan.a0[lid][e], a1 = g_plan.a1[lid][e];
    w0v[e] = (a0 >= 0) ? avalS[a0] : 0.f;
    w1v[e] = (a1 >= 0) ? avalS[a1] : 0.f;
  }
  const int d0 = g_plan.d0[lid], d1 = g_plan.d1[lid];
  const int b0c = g_plan.b0[lid], b1c = g_plan.b1[lid];
  const int o0 = g_plan.o0[lid], o1 = g_plan.o1[lid];
  const int scol = g_plan.scol[lid];
  const float sm1 = (float)g_plan.sm1[lid], sm2 = (float)g_plan.sm2[lid];
  __syncthreads();   // Bt_lds, avalS, seq_lds final

  float* ob = out + (size_t)blockIdx.x * T_LEN * S;
  int etn = 0;
  float u0 = 0.f, u1 = 0.f;

  if (wv == 0) {  // init: row 0 into alpha + ring row 0
    const int e0s = seq_lds[0];
    const float ui0 = (d0 < 108) ? RESCALE_TARGET * pi_lds[d0] * Bt_lds[e0s * S + d0] : 0.f;
    const float ui1 = (d1 < 108) ? RESCALE_TARGET * pi_lds[d1] * Bt_lds[e0s * S + d1] : 0.f;
    alpha_lds[d0] = ui0;
    alpha_lds[d1] = ui1;
    for (int i = lid; i < S; i += 64) ring[i] = alpha_lds[i];
    etn = seq_lds[1];
  }

  // ---------- main: producer fills group k (k<128); consumer drains+normalizes
  // ---------- group k-1; one barrier per group ----------
  for (int k = 0; k <= 128; k++) {
    if (wv == 0) {
      if (k < 128) {
        const int tb = 16 * k;
        const int hb = (k & 1) << 4;
        int rs = hb * S;
        if (k == 0) {
          rs += S;   // t starts at 1
          for (int j = 1; j < 15; j++) {
            const int ec = etn; etn = seq_lds[j + 1];
            PSTEP(ec, rs, rs - S, 0, 1)
            rs += S;
          }
          const int ec = etn; etn = seq_lds[16];
          PSTEP(ec, rs, rs - S, 1, 1)
        } else {
          {  // j = 0: row t-1 is in the half being drained -> no scol write
            const int ec = etn; etn = seq_lds[tb + 1];
            PSTEP(ec, rs, 0, 0, 0)
            rs += S;
          }
          for (int j = 1; j < 15; j++) {
            const int ec = etn; etn = seq_lds[tb + j + 1];
            PSTEP(ec, rs, rs - S, 0, 1)
            rs += S;
          }
          const int ec = etn; etn = seq_lds[tb + 16];   // padded: always in-bounds
          PSTEP(ec, rs, rs - S, 1, 1)
        }
        if (scol >= 0) {  // end-of-group: split-col value for the group's last row
          const float x0 = alpha_lds[gsrc[0]];
          const float x1 = alpha_lds[gsrc[1]];
          const float x2 = alpha_lds[gsrc[2]];
          ring[(hb + 15) * S + scol] = x0 + sm1 * x1 + sm2 * x2;
        }
      }
    } else {
      if (k > 0) {  // drain + normalize group k-1 (other ring half)
        // 4 lanes per row; read <=7 float4s once, 2-shfl row sum, scale, store.
        const int g = k - 1;
        const float4* srcb4 = (const float4*)&ring[(g & 1) * 16 * S];
        float4* dstb4 = (float4*)(ob + (size_t)g * 16 * S);
        const int r = lid >> 2;
        const int j = lid & 3;
        float4 v0, v1, v2, v3, v4, v5, v6;
        float psum = 0.f;
        v6 = make_float4(0.f, 0.f, 0.f, 0.f);
        const int base4 = r * 27 + j;
        v0 = srcb4[base4];
        v1 = srcb4[base4 + 4];
        v2 = srcb4[base4 + 8];
        v3 = srcb4[base4 + 12];
        v4 = srcb4[base4 + 16];
        v5 = srcb4[base4 + 20];
        if (j < 3) v6 = srcb4[base4 + 24];
        psum = v0.x + v0.y + v0.z + v0.w + v1.x + v1.y + v1.z + v1.w
             + v2.x + v2.y + v2.z + v2.w + v3.x + v3.y + v3.z + v3.w
             + v4.x + v4.y + v4.z + v4.w + v5.x + v5.y + v5.z + v5.w
             + v6.x + v6.y + v6.z + v6.w;
        psum += __shfl_xor(psum, 1, 64);
        psum += __shfl_xor(psum, 2, 64);
        const float iv = 1.f / psum;
        v0.x *= iv; v0.y *= iv; v0.z *= iv; v0.w *= iv;
        v1.x *= iv; v1.y *= iv; v1.z *= iv; v1.w *= iv;
        v2.x *= iv; v2.y *= iv; v2.z *= iv; v2.w *= iv;
        v3.x *= iv; v3.y *= iv; v3.z *= iv; v3.w *= iv;
        v4.x *= iv; v4.y *= iv; v4.z *= iv; v4.w *= iv;
        v5.x *= iv; v5.y *= iv; v5.z *= iv; v5.w *= iv;
        v6.x *= iv; v6.y *= iv; v6.z *= iv; v6.w *= iv;
        dstb4[base4] = v0;
        dstb4[base4 + 4] = v1;
        dstb4[base4 + 8] = v2;
        dstb4[base4 + 12] = v3;
        dstb4[base4 + 16] = v4;
        dstb4[base4 + 20] = v5;
        if (j < 3) dstb4[base4 + 24] = v6;
      }
    }
    __syncthreads();
  }
}

extern "C" void kernel_launch(void* const* d_in, const int* in_sizes, int n_in,
                              void* d_out, int out_size, void* d_ws, size_t ws_size,
                              hipStream_t stream) {
  const int* inp = (const int*)d_in[0];
  const float* w = (const float*)d_in[1];
  const float* ek = (const float*)d_in[2];
  const float* ik = (const float*)d_in[3];
  float* out = (float*)d_out;
  (void)d_ws; (void)ws_size; (void)in_sizes; (void)n_in; (void)out_size;
  hmm_scan_kernel<<<N_BATCH, 128, 0, stream>>>(inp, w, ek, ik, out);
}

// Round 16
// 375.460 us; speedup vs baseline: 1.7223x; 1.1009x over previous
//
#include <hip/hip_runtime.h>
#include <cstdint>
#include <cstddef>

#define S 108
#define NEMIT 126
#define T_LEN 2048
#define N_BATCH 256
#define MAXG 10    // max gather entries per lane after balancing
#define MAXNE 6500 // emission nnz upper bound (actual 6432)
#define NE_A 280   // A-matrix nnz
#define RW 132     // ring row width: 108 states + 14 pieces + trash; 132%32=4 rotates banks

#define RESCALE_TARGET 1e24f

// ================= compile-time emission structure =================
struct EmTab {
  short row[MAXNE];
  short col[MAXNE];
  short widx[MAXNE];
  int rp[S + 1];
  int n;
  int nw;
};

constexpr int cmask(int sym, int add4) {
  int m = (sym == 4) ? 0xF : (1 << sym);
  if (add4) m |= 0x10;
  return m;
}

constexpr EmTab buildEm() {
  EmTab E{};
  int n = 0, k = 0;
  auto doCall = [&](int stt, int s0_, int s1_, int s2_, int xm_, int tr_) {
    const int m0 = cmask(s0_, xm_ < 2 ? 1 : 0);
    const int m1 = cmask(s1_, xm_ < 1 ? 1 : 0);
    const int m2 = cmask(s2_, 0);
    for (int x0 = 0; x0 < 5; x0++) {
      if (!((m0 >> x0) & 1)) continue;
      for (int x1 = 0; x1 < 5; x1++) {
        if (!((m1 >> x1) & 1)) continue;
        if (x0 != 4 && x1 == 4) continue;
        for (int x2 = 0; x2 < 5; x2++) {
          if (!((m2 >> x2) & 1)) continue;
          E.row[n] = (short)stt;
          E.col[n] = (short)(x0 * 25 + x1 * 5 + x2);
          E.widx[n] = (short)(tr_ ? k++ : -1);
          n++;
        }
      }
    }
  };
  doCall(0, 4, 4, 4, 0, 1);
  doCall(1, 4, 4, 0, 0, 1);
  doCall(2, 4, 0, 3, 0, 1);
  doCall(3, 0, 3, 2, 2, 0);
  doCall(4, 3, 2, 4, 2, 1);
  doCall(5, 2, 4, 4, 2, 1);
  for (int s = 6; s <= 51; s++) doCall(s, 4, 4, 4, 2, 1);
  doCall(52, 4, 4, 3, 2, 1);
  doCall(53, 4, 3, 0, 2, 1);
  doCall(53, 4, 3, 2, 2, 1);
  doCall(54, 3, 0, 0, 2, 0);
  doCall(54, 3, 0, 2, 2, 0);
  doCall(54, 3, 2, 0, 2, 0);
  doCall(55, 4, 4, 4, 2, 1);
  for (int s = 56; s <= 106; s++) doCall(s, 4, 4, 4, 2, 1);
  E.row[n] = 107; E.col[n] = 125; E.widx[n] = -1; n++;
  E.n = n; E.nw = k;
  for (int r = 0; r <= S; r++) E.rp[r] = 0;
  for (int e = 0; e < n; e++) E.rp[E.row[e] + 1]++;
  for (int r = 0; r < S; r++) E.rp[r + 1] += E.rp[r];
  return E;
}

constexpr EmTab EM_HOST = buildEm();
static_assert(EM_HOST.n <= MAXNE && EM_HOST.n > 6000, "emission count sanity");
__device__ const EmTab g_em = EM_HOST;

// ================= compile-time A structure + full gather plan =================
struct APlan {
  short vcode[NE_A], vwi[NE_A];
  short aidx[NE_A];
  short arp[S + 1];
  unsigned char src[64][MAXG];
  short a0[64][MAXG], a1[64][MAXG];
  unsigned char d0[64], d1[64], b0[64], b1[64];
  short scol[64];
  unsigned char sm1[64], sm2[64];
  int maxload, ncons, np;
};

constexpr APlan buildPlan() {
  APlan P{};
  short arow[NE_A] = {}, acol[NE_A] = {};
  int ne = 0;
  auto AD = [&](int r, int c, int code, int wi) {
    arow[ne] = (short)r; acol[ne] = (short)c;
    P.vcode[ne] = (short)code; P.vwi[ne] = (short)wi; ne++;
  };
  AD(0, 0, 2, 0); AD(0, 1, 1, 0); AD(1, 2, 0, 0); AD(2, 3, 0, 0);
  for (int i = 0; i < 16; i++) AD(3 + 3 * i, 4 + 3 * i, 1, 1 + i);
  for (int i = 0; i < 16; i++) AD(4 + 3 * i, 5 + 3 * i, 0, 0);
  for (int i = 0; i < 16; i++) AD(5 + 3 * i, 6 + 3 * i, 0, 0);
  for (int i = 0; i <= 16; i++) AD(3 + 3 * i, 56 + 3 * i, 1, 17 + i);
  AD(51, 52, 1, 34);
  for (int i = 0; i <= 16; i++) AD(56 + 3 * i, 57 + 3 * i, 0, 0);
  for (int i = 0; i <= 16; i++) AD(57 + 3 * i, 58 + 3 * i, 0, 0);
  for (int i = 0; i <= 16; i++) AD(58 + 3 * i, 4 + 3 * i, 1, 35 + i);
  for (int i = 0; i <= 16; i++) AD(58 + 3 * i, 56 + 3 * i, 2, 35 + i);
  for (int a = 0; a < 16; a++)
    for (int jj = a + 1; jj <= 16; jj++) AD(3 + 3 * a, 4 + 3 * jj, 3, jj - a + 1);
  AD(52, 53, 0, 0); AD(53, 54, 0, 0); AD(54, 55, 0, 0);
  AD(55, 55, 0, 0); AD(55, 107, 0, 0); AD(107, 107, 0, 0);

  int rc[S + 1] = {};
  for (int e = 0; e < ne; e++) rc[arow[e] + 1]++;
  for (int r = 0; r < S; r++) rc[r + 1] += rc[r];
  for (int r = 0; r <= S; r++) P.arp[r] = (short)rc[r];
  int fill[S] = {};
  for (int e = 0; e < ne; e++) { const int r = arow[e]; P.aidx[rc[r] + fill[r]] = (short)e; fill[r]++; }

  int ccnt[S] = {}; short clist[S][18] = {};
  for (int e = 0; e < ne; e++) { const int c = acol[e]; clist[c][ccnt[c]] = (short)e; ccnt[c]++; }
  int npcA[S] = {};
  short pdefs[16][6] = {}; int pcnt[16] = {}; short pcol[16] = {};
  int np = 0;
  for (int c = 0; c < S; c++) {
    while (ccnt[c] > 8) {
      const int base = ccnt[c] - 6;
      for (int j = 0; j < 6; j++) pdefs[np][j] = clist[c][base + j];
      pcnt[np] = 6; pcol[np] = (short)c;
      npcA[c]++; ccnt[c] -= 6; np++;
    }
  }
  int lload[64] = {}, lnit[64] = {};
  for (int l = 0; l < 64; l++) {
    for (int e = 0; e < MAXG; e++) { P.src[l][e] = 0; P.a0[l][e] = -1; P.a1[l][e] = -1; }
    P.d0[l] = 127; P.d1[l] = 127; P.b0[l] = 0; P.b1[l] = 0;
    P.scol[l] = -1; P.sm1[l] = 0; P.sm2[l] = 0;
  }
  int ncons = 0;
  for (int c = 0; c < S; c++) {
    if (ccnt[c] == 1) {
      const int e0 = clist[c][0];
      const int r = arow[e0];
      if (npcA[r] > 0) {
        const int l = 54 + ncons; ncons++;
        int k = 0;
        P.src[l][k] = (unsigned char)r; P.a0[l][k] = (short)e0; k++;
        for (int p = 0; p < np; p++)
          if (pcol[p] == r) { P.src[l][k] = (unsigned char)(108 + p); P.a0[l][k] = (short)e0; k++; }
        P.d0[l] = (unsigned char)c; P.b0[l] = (unsigned char)c;
        P.scol[l] = (short)r;
        P.sm1[l] = (k >= 2) ? 1 : 0; P.sm2[l] = (k >= 3) ? 1 : 0;
        lload[l] = k; lnit[l] = 1;
        ccnt[c] = 0;
      }
    }
  }
  int rr = 0;
  auto pickLane = [&](int L) {
    for (;;) {
      const int pos = rr & 127; rr++;
      const int l = (pos < 64) ? pos : (127 - pos);
      if (lnit[l] < 2 && lload[l] + L <= MAXG) return l;
    }
  };
  for (int th = 8; th >= 1; th--) {
    for (int p = 0; p < np; p++) {
      if (pcnt[p] != th) continue;
      const int l = pickLane(th);
      const int it = lnit[l], base = lload[l];
      for (int j = 0; j < th; j++) {
        P.src[l][base + j] = (unsigned char)arow[pdefs[p][j]];
        if (it == 0) P.a0[l][base + j] = pdefs[p][j];
        else         P.a1[l][base + j] = pdefs[p][j];
      }
      if (it == 0) { P.d0[l] = (unsigned char)(108 + p); P.b0[l] = (unsigned char)pcol[p]; }
      else         { P.d1[l] = (unsigned char)(108 + p); P.b1[l] = (unsigned char)pcol[p]; }
      lload[l] = base + th; lnit[l] = it + 1;
    }
    for (int c = 0; c < S; c++) {
      if (ccnt[c] != th) continue;
      const int l = pickLane(th);
      const int it = lnit[l], base = lload[l];
      for (int j = 0; j < th; j++) {
        P.src[l][base + j] = (unsigned char)arow[clist[c][j]];
        if (it == 0) P.a0[l][base + j] = clist[c][j];
        else         P.a1[l][base + j] = clist[c][j];
      }
      if (it == 0) { P.d0[l] = (unsigned char)c; P.b0[l] = (unsigned char)c; }
      else         { P.d1[l] = (unsigned char)c; P.b1[l] = (unsigned char)c; }
      lload[l] = base + th; lnit[l] = it + 1;
    }
  }
  int ml = 0;
  for (int l = 0; l < 64; l++) ml = (lload[l] > ml) ? lload[l] : ml;
  P.maxload = ml; P.ncons = ncons; P.np = np;
  return P;
}

constexpr APlan PLAN_HOST = buildPlan();
static_assert(PLAN_HOST.maxload <= MAXG, "lane gather overflow");
static_assert(PLAN_HOST.ncons <= 10, "too many consumer lanes");
static_assert(PLAN_HOST.np <= 14, "piece slots must fit cols 108..121");
__device__ const APlan g_plan = PLAN_HOST;

// One producer step, ring-as-alpha. SYM_: symbol. RS_: ring base of row t.
// GB_: ring base of row t-1 (gather source + scol destination).
// RESC_: rescale (compile-time). SCOK_: emit split-col write for row t-1.
// W0_: item0 weight array (w0v normally; w0j at group-boundary j==0 steps,
// where the gather source row's split-state slots already hold FULL values).
#define PSTEP(SYM_, RS_, GB_, RESC_, SCOK_, W0_)                          \
  {                                                                       \
    const int ecur_ = (SYM_);                                             \
    float x[MAXG];                                                        \
    _Pragma("unroll")                                                     \
    for (int e = 0; e < MAXG; e++) x[e] = ring[(GB_) + gsrc[e]];          \
    const float bt0_ = Bt_lds[ecur_ * S + b0c];                           \
    const float bt1_ = Bt_lds[ecur_ * S + b1c];                           \
    float aA_ = 0.f, aB_ = 0.f, bA_ = 0.f, bB_ = 0.f;                     \
    _Pragma("unroll")                                                     \
    for (int e = 0; e < MAXG; e += 2) {                                   \
      aA_ += x[e] * W0_[e];     aB_ += x[e + 1] * W0_[e + 1];             \
      bA_ += x[e] * w1v[e];     bB_ += x[e + 1] * w1v[e + 1];             \
    }                                                                     \
    u0 = (aA_ + aB_) * bt0_;                                              \
    u1 = (bA_ + bB_) * bt1_;                                              \
    const float sumv_ = x[0] + sm1 * x[1] + sm2 * x[2];                   \
    if (RESC_) {                                                          \
      float m_ = fmaxf(u0, u1);                                           \
      _Pragma("unroll")                                                   \
      for (int msk_ = 1; msk_ < 64; msk_ <<= 1)                           \
        m_ = fmaxf(m_, __shfl_xor(m_, msk_, 64));                         \
      const float r_ = RESCALE_TARGET / m_;                               \
      u0 *= r_; u1 *= r_;                                                 \
    }                                                                     \
    ring[(RS_) + d0] = u0;                                                \
    ring[(RS_) + d1] = u1;                                                \
    if (SCOK_) {                                                          \
      const int a2_ = (scol >= 0) ? (GB_) + scol : (GB_) + 123 + (lid & 3); \
      ring[a2_] = sumv_;                                                  \
    }                                                                     \
  }

// ================= scan kernel: ring-as-alpha producer + light consumer ========
__global__ __launch_bounds__(128, 1) void hmm_scan_kernel(
    const int* __restrict__ inp, const float* __restrict__ w,
    const float* __restrict__ ek, const float* __restrict__ ik,
    float* __restrict__ out) {
  __shared__ __align__(16) float Bt_lds[NEMIT * S];
  __shared__ __align__(16) float ring[32 * RW];      // 32 rows x 132: state+pieces+trash
  __shared__ float pi_lds[S];
  __shared__ float avalS[NE_A];
  __shared__ __align__(16) int seq_lds[T_LEN + 16];  // padded: no bounds select

  const int tid = threadIdx.x;
  const int lid = tid & 63;
  const int wv = tid >> 6;   // 0 = producer, 1 = consumer

  // ---------- setup (both waves cooperate) ----------
  for (int i = tid; i < NEMIT * S; i += 128) Bt_lds[i] = 0.f;

  {  // seq -> LDS (int4 loads); pad
    const int4* s4 = (const int4*)(inp + (size_t)blockIdx.x * T_LEN);
    int4* d4 = (int4*)seq_lds;
    for (int i = tid; i < T_LEN / 4; i += 128) d4[i] = s4[i];
    if (tid < 4) d4[T_LEN / 4 + tid] = s4[T_LEN / 4 - 1];
  }

  if (wv == 0) {  // pi = softmax(ik)
    float q0 = ik[lid];
    float q1 = (lid + 64 < S) ? ik[lid + 64] : -1e30f;
    float mx = fmaxf(q0, q1);
#pragma unroll
    for (int msk = 1; msk < 64; msk <<= 1) mx = fmaxf(mx, __shfl_xor(mx, msk, 64));
    float e0v = expf(q0 - mx);
    float e1v = (lid + 64 < S) ? expf(q1 - mx) : 0.f;
    float zz = e0v + e1v;
#pragma unroll
    for (int msk = 1; msk < 64; msk <<= 1) zz += __shfl_xor(zz, msk, 64);
    const float rz = 1.f / zz;
    pi_lds[lid] = e0v * rz;
    if (lid + 64 < S) pi_lds[lid + 64] = e1v * rz;
  }

  {  // A values from descriptors
    const float wk = w[52];
    const float aw = fabsf(wk);
    const float sgnw = (wk > 0.f) ? 1.f : ((wk < 0.f) ? -1.f : 0.f);
    for (int e = tid; e < NE_A; e += 128) {
      const int code = g_plan.vcode[e];
      const int wi = g_plan.vwi[e];
      float v;
      if (code == 0) v = 1.f;
      else if (code == 1) v = w[wi];
      else if (code == 2) v = 1.f - w[wi];
      else {
        const float pw = powf(aw, (float)wi);
        v = 1.f - ((wi & 1) ? sgnw : 1.f) * pw;
      }
      avalS[e] = v;
    }
  }
  __syncthreads();

  if (tid < S) {  // A row-softmax
    const int b = g_plan.arp[tid], e2 = g_plan.arp[tid + 1];
    float m = -1e30f;
    for (int j = b; j < e2; j++) m = fmaxf(m, avalS[g_plan.aidx[j]]);
    float z = 0.f;
    for (int j = b; j < e2; j++) z += expf(avalS[g_plan.aidx[j]] - m);
    const float rz = 1.f / z;
    for (int j = b; j < e2; j++) {
      const int ii = g_plan.aidx[j];
      avalS[ii] = expf(avalS[ii] - m) * rz;
    }
  }
  __syncthreads();

  if (tid < S) {  // B row-softmax
    const int r = tid;
    const int b = g_em.rp[r], e2 = g_em.rp[r + 1];
    float m = -1e30f;
    for (int e = b; e < e2; e++) {
      const int wi = g_em.widx[e];
      m = fmaxf(m, (wi >= 0) ? ek[wi] : 1.f);
    }
    float z = 0.f;
    for (int e = b; e < e2; e++) {
      const int wi = g_em.widx[e];
      z += expf(((wi >= 0) ? ek[wi] : 1.f) - m);
    }
    const float rz = 1.f / z;
    for (int e = b; e < e2; e++) {
      const int wi = g_em.widx[e];
      Bt_lds[(int)g_em.col[e] * S + r] = expf(((wi >= 0) ? ek[wi] : 1.f) - m) * rz;
    }
  }

  // plan -> registers
  int gsrc[MAXG]; float w0v[MAXG], w1v[MAXG];
#pragma unroll
  for (int e = 0; e < MAXG; e++) {
    gsrc[e] = g_plan.src[lid][e];
    const int a0 = g_plan.a0[lid][e], a1 = g_plan.a1[lid][e];
    w0v[e] = (a0 >= 0) ? avalS[a0] : 0.f;
    w1v[e] = (a1 >= 0) ? avalS[a1] : 0.f;
  }
  const int d0 = g_plan.d0[lid], d1 = g_plan.d1[lid];
  const int b0c = g_plan.b0[lid], b1c = g_plan.b1[lid];
  const int scol = g_plan.scol[lid];
  const float sm1 = (float)g_plan.sm1[lid], sm2 = (float)g_plan.sm2[lid];

  // j==0 weights: at group boundaries the source row's split-state slot holds
  // the FULL value (end-of-group reconstruction overwrote the partial), so
  // consumer lanes must not add the piece slots again. Consumer item0 is
  // {split-state, piece(, piece)}; positions 1,2 are pieces or already 0.
  float w0j[MAXG];
#pragma unroll
  for (int e = 0; e < MAXG; e++) w0j[e] = w0v[e];
  if (scol >= 0) { w0j[1] = 0.f; w0j[2] = 0.f; }
  __syncthreads();   // Bt_lds, avalS, seq_lds final

  float* ob = out + (size_t)blockIdx.x * T_LEN * S;
  int etn = 0;
  float u0 = 0.f, u1 = 0.f;

  if (wv == 0) {  // init: row 0 directly into ring (pieces get 0)
    const int e0s = seq_lds[0];
    const float ui0 = (d0 < 108) ? RESCALE_TARGET * pi_lds[d0] * Bt_lds[e0s * S + d0] : 0.f;
    const float ui1 = (d1 < 108) ? RESCALE_TARGET * pi_lds[d1] * Bt_lds[e0s * S + d1] : 0.f;
    ring[d0] = ui0;
    ring[d1] = ui1;
    etn = seq_lds[1];
  }

  // ---------- main: producer fills group k (k<128); consumer drains+normalizes
  // ---------- group k-1; one barrier per group ----------
  for (int k = 0; k <= 128; k++) {
    if (wv == 0) {
      if (k < 128) {
        const int tb = 16 * k;
        const int hb = (k & 1) << 4;
        int rs = hb * RW;
        if (k == 0) {
          rs += RW;   // t starts at 1
          for (int j = 1; j < 15; j++) {
            const int ec = etn; etn = seq_lds[j + 1];
            PSTEP(ec, rs, rs - RW, 0, 1, w0v)
            rs += RW;
          }
          const int ec = etn; etn = seq_lds[16];
          PSTEP(ec, rs, rs - RW, 1, 1, w0v)
        } else {
          const int gb0 = (((k & 1) ^ 1) * 16 + 15) * RW;   // other half's last row
          {  // j = 0: source row holds FULL split-state values -> w0j weights
            const int ec = etn; etn = seq_lds[tb + 1];
            PSTEP(ec, rs, gb0, 0, 0, w0j)
            rs += RW;
          }
          for (int j = 1; j < 15; j++) {
            const int ec = etn; etn = seq_lds[tb + j + 1];
            PSTEP(ec, rs, rs - RW, 0, 1, w0v)
            rs += RW;
          }
          const int ec = etn; etn = seq_lds[tb + 16];
          PSTEP(ec, rs, rs - RW, 1, 1, w0v)
        }
        if (scol >= 0) {  // end-of-group: full split-state value for last row
          const int base = (hb + 15) * RW;
          const float x0 = ring[base + gsrc[0]];
          const float x1 = ring[base + gsrc[1]];
          const float x2 = ring[base + gsrc[2]];
          ring[base + scol] = x0 + sm1 * x1 + sm2 * x2;
        }
      }
    } else {
      if (k > 0) {  // drain + normalize group k-1 (other ring half)
        // 4 lanes per row; read <=7 float4s once (stride 33/row), 2-shfl row
        // sum, scale, store to global (stride 27/row).
        const int g = k - 1;
        const float4* srcb4 = (const float4*)&ring[(g & 1) * 16 * RW];
        float4* dstb4 = (float4*)(ob + (size_t)g * 16 * S);
        const int r = lid >> 2;
        const int j = lid & 3;
        float4 v0, v1, v2, v3, v4, v5, v6;
        v6 = make_float4(0.f, 0.f, 0.f, 0.f);
        const int sbase = r * 33 + j;   // RW/4 = 33 float4 per ring row
        const int dbase = r * 27 + j;   // S/4 = 27 float4 per output row
        v0 = srcb4[sbase];
        v1 = srcb4[sbase + 4];
        v2 = srcb4[sbase + 8];
        v3 = srcb4[sbase + 12];
        v4 = srcb4[sbase + 16];
        v5 = srcb4[sbase + 20];
        if (j < 3) v6 = srcb4[sbase + 24];
        float psum = v0.x + v0.y + v0.z + v0.w + v1.x + v1.y + v1.z + v1.w
                   + v2.x + v2.y + v2.z + v2.w + v3.x + v3.y + v3.z + v3.w
                   + v4.x + v4.y + v4.z + v4.w + v5.x + v5.y + v5.z + v5.w
                   + v6.x + v6.y + v6.z + v6.w;
        psum += __shfl_xor(psum, 1, 64);
        psum += __shfl_xor(psum, 2, 64);
        const float iv = 1.f / psum;
        v0.x *= iv; v0.y *= iv; v0.z *= iv; v0.w *= iv;
        v1.x *= iv; v1.y *= iv; v1.z *= iv; v1.w *= iv;
        v2.x *= iv; v2.y *= iv; v2.z *= iv; v2.w *= iv;
        v3.x *= iv; v3.y *= iv; v3.z *= iv; v3.w *= iv;
        v4.x *= iv; v4.y *= iv; v4.z *= iv; v4.w *= iv;
        v5.x *= iv; v5.y *= iv; v5.z *= iv; v5.w *= iv;
        v6.x *= iv; v6.y *= iv; v6.z *= iv; v6.w *= iv;
        dstb4[dbase] = v0;
        dstb4[dbase + 4] = v1;
        dstb4[dbase + 8] = v2;
        dstb4[dbase + 12] = v3;
        dstb4[dbase + 16] = v4;
        dstb4[dbase + 20] = v5;
        if (j < 3) dstb4[dbase + 24] = v6;
      }
    }
    __syncthreads();
  }
}

extern "C" void kernel_launch(void* const* d_in, const int* in_sizes, int n_in,
                              void* d_out, int out_size, void* d_ws, size_t ws_size,
                              hipStream_t stream) {
  const int* inp = (const int*)d_in[0];
  const float* w = (const float*)d_in[1];
  const float* ek = (const float*)d_in[2];
  const float* ik = (const float*)d_in[3];
  float* out = (float*)d_out;
  (void)d_ws; (void)ws_size; (void)in_sizes; (void)n_in; (void)out_size;
  hmm_scan_kernel<<<N_BATCH, 128, 0, stream>>>(inp, w, ek, ik, out);
}

// Round 18
// 370.583 us; speedup vs baseline: 1.7450x; 1.0132x over previous
//
#include <hip/hip_runtime.h>
#include <cstdint>
#include <cstddef>

#define S 108
#define NEMIT 126
#define T_LEN 2048
#define N_BATCH 256
#define MAXG 10    // max gather entries per lane after balancing
#define MAXNE 6500 // emission nnz upper bound (actual 6432)
#define NE_A 280   // A-matrix nnz
#define RW 132     // ring row width: 108 states + 14 pieces + trash; 132%32=4 rotates banks

// Rescale every 16 steps. Cadence constraint: r = TARGET/m must stay < 3.4e38;
// with decay ~0.016/step, m after 15 steps ~ TARGET*1e-28 -> r ~ 1e28. A
// 32-step cadence overflows r (R17 NaN). TARGET value itself cancels in norm.
#define RESCALE_TARGET 1e24f

// ================= compile-time emission structure =================
struct EmTab {
  short row[MAXNE];
  short col[MAXNE];
  short widx[MAXNE];
  int rp[S + 1];
  int n;
  int nw;
};

constexpr int cmask(int sym, int add4) {
  int m = (sym == 4) ? 0xF : (1 << sym);
  if (add4) m |= 0x10;
  return m;
}

constexpr EmTab buildEm() {
  EmTab E{};
  int n = 0, k = 0;
  auto doCall = [&](int stt, int s0_, int s1_, int s2_, int xm_, int tr_) {
    const int m0 = cmask(s0_, xm_ < 2 ? 1 : 0);
    const int m1 = cmask(s1_, xm_ < 1 ? 1 : 0);
    const int m2 = cmask(s2_, 0);
    for (int x0 = 0; x0 < 5; x0++) {
      if (!((m0 >> x0) & 1)) continue;
      for (int x1 = 0; x1 < 5; x1++) {
        if (!((m1 >> x1) & 1)) continue;
        if (x0 != 4 && x1 == 4) continue;
        for (int x2 = 0; x2 < 5; x2++) {
          if (!((m2 >> x2) & 1)) continue;
          E.row[n] = (short)stt;
          E.col[n] = (short)(x0 * 25 + x1 * 5 + x2);
          E.widx[n] = (short)(tr_ ? k++ : -1);
          n++;
        }
      }
    }
  };
  doCall(0, 4, 4, 4, 0, 1);
  doCall(1, 4, 4, 0, 0, 1);
  doCall(2, 4, 0, 3, 0, 1);
  doCall(3, 0, 3, 2, 2, 0);
  doCall(4, 3, 2, 4, 2, 1);
  doCall(5, 2, 4, 4, 2, 1);
  for (int s = 6; s <= 51; s++) doCall(s, 4, 4, 4, 2, 1);
  doCall(52, 4, 4, 3, 2, 1);
  doCall(53, 4, 3, 0, 2, 1);
  doCall(53, 4, 3, 2, 2, 1);
  doCall(54, 3, 0, 0, 2, 0);
  doCall(54, 3, 0, 2, 2, 0);
  doCall(54, 3, 2, 0, 2, 0);
  doCall(55, 4, 4, 4, 2, 1);
  for (int s = 56; s <= 106; s++) doCall(s, 4, 4, 4, 2, 1);
  E.row[n] = 107; E.col[n] = 125; E.widx[n] = -1; n++;
  E.n = n; E.nw = k;
  for (int r = 0; r <= S; r++) E.rp[r] = 0;
  for (int e = 0; e < n; e++) E.rp[E.row[e] + 1]++;
  for (int r = 0; r < S; r++) E.rp[r + 1] += E.rp[r];
  return E;
}

constexpr EmTab EM_HOST = buildEm();
static_assert(EM_HOST.n <= MAXNE && EM_HOST.n > 6000, "emission count sanity");
__device__ const EmTab g_em = EM_HOST;

// ================= compile-time A structure + full gather plan =================
struct APlan {
  short vcode[NE_A], vwi[NE_A];
  short aidx[NE_A];
  short arp[S + 1];
  unsigned char src[64][MAXG];
  short a0[64][MAXG], a1[64][MAXG];
  unsigned char d0[64], d1[64], b0[64], b1[64];
  short scol[64];
  unsigned char sm1[64], sm2[64];
  int maxload, ncons, np;
};

constexpr APlan buildPlan() {
  APlan P{};
  short arow[NE_A] = {}, acol[NE_A] = {};
  int ne = 0;
  auto AD = [&](int r, int c, int code, int wi) {
    arow[ne] = (short)r; acol[ne] = (short)c;
    P.vcode[ne] = (short)code; P.vwi[ne] = (short)wi; ne++;
  };
  AD(0, 0, 2, 0); AD(0, 1, 1, 0); AD(1, 2, 0, 0); AD(2, 3, 0, 0);
  for (int i = 0; i < 16; i++) AD(3 + 3 * i, 4 + 3 * i, 1, 1 + i);
  for (int i = 0; i < 16; i++) AD(4 + 3 * i, 5 + 3 * i, 0, 0);
  for (int i = 0; i < 16; i++) AD(5 + 3 * i, 6 + 3 * i, 0, 0);
  for (int i = 0; i <= 16; i++) AD(3 + 3 * i, 56 + 3 * i, 1, 17 + i);
  AD(51, 52, 1, 34);
  for (int i = 0; i <= 16; i++) AD(56 + 3 * i, 57 + 3 * i, 0, 0);
  for (int i = 0; i <= 16; i++) AD(57 + 3 * i, 58 + 3 * i, 0, 0);
  for (int i = 0; i <= 16; i++) AD(58 + 3 * i, 4 + 3 * i, 1, 35 + i);
  for (int i = 0; i <= 16; i++) AD(58 + 3 * i, 56 + 3 * i, 2, 35 + i);
  for (int a = 0; a < 16; a++)
    for (int jj = a + 1; jj <= 16; jj++) AD(3 + 3 * a, 4 + 3 * jj, 3, jj - a + 1);
  AD(52, 53, 0, 0); AD(53, 54, 0, 0); AD(54, 55, 0, 0);
  AD(55, 55, 0, 0); AD(55, 107, 0, 0); AD(107, 107, 0, 0);

  int rc[S + 1] = {};
  for (int e = 0; e < ne; e++) rc[arow[e] + 1]++;
  for (int r = 0; r < S; r++) rc[r + 1] += rc[r];
  for (int r = 0; r <= S; r++) P.arp[r] = (short)rc[r];
  int fill[S] = {};
  for (int e = 0; e < ne; e++) { const int r = arow[e]; P.aidx[rc[r] + fill[r]] = (short)e; fill[r]++; }

  int ccnt[S] = {}; short clist[S][18] = {};
  for (int e = 0; e < ne; e++) { const int c = acol[e]; clist[c][ccnt[c]] = (short)e; ccnt[c]++; }
  int npcA[S] = {};
  short pdefs[16][6] = {}; int pcnt[16] = {}; short pcol[16] = {};
  int np = 0;
  for (int c = 0; c < S; c++) {
    while (ccnt[c] > 8) {
      const int base = ccnt[c] - 6;
      for (int j = 0; j < 6; j++) pdefs[np][j] = clist[c][base + j];
      pcnt[np] = 6; pcol[np] = (short)c;
      npcA[c]++; ccnt[c] -= 6; np++;
    }
  }
  int lload[64] = {}, lnit[64] = {};
  for (int l = 0; l < 64; l++) {
    for (int e = 0; e < MAXG; e++) { P.src[l][e] = 0; P.a0[l][e] = -1; P.a1[l][e] = -1; }
    P.d0[l] = 127; P.d1[l] = 127; P.b0[l] = 0; P.b1[l] = 0;
    P.scol[l] = -1; P.sm1[l] = 0; P.sm2[l] = 0;
  }
  int ncons = 0;
  for (int c = 0; c < S; c++) {
    if (ccnt[c] == 1) {
      const int e0 = clist[c][0];
      const int r = arow[e0];
      if (npcA[r] > 0) {
        const int l = 54 + ncons; ncons++;
        int k = 0;
        P.src[l][k] = (unsigned char)r; P.a0[l][k] = (short)e0; k++;
        for (int p = 0; p < np; p++)
          if (pcol[p] == r) { P.src[l][k] = (unsigned char)(108 + p); P.a0[l][k] = (short)e0; k++; }
        P.d0[l] = (unsigned char)c; P.b0[l] = (unsigned char)c;
        P.scol[l] = (short)r;
        P.sm1[l] = (k >= 2) ? 1 : 0; P.sm2[l] = (k >= 3) ? 1 : 0;
        lload[l] = k; lnit[l] = 1;
        ccnt[c] = 0;
      }
    }
  }
  int rr = 0;
  auto pickLane = [&](int L) {
    for (;;) {
      const int pos = rr & 127; rr++;
      const int l = (pos < 64) ? pos : (127 - pos);
      if (lnit[l] < 2 && lload[l] + L <= MAXG) return l;
    }
  };
  for (int th = 8; th >= 1; th--) {
    for (int p = 0; p < np; p++) {
      if (pcnt[p] != th) continue;
      const int l = pickLane(th);
      const int it = lnit[l], base = lload[l];
      for (int j = 0; j < th; j++) {
        P.src[l][base + j] = (unsigned char)arow[pdefs[p][j]];
        if (it == 0) P.a0[l][base + j] = pdefs[p][j];
        else         P.a1[l][base + j] = pdefs[p][j];
      }
      if (it == 0) { P.d0[l] = (unsigned char)(108 + p); P.b0[l] = (unsigned char)pcol[p]; }
      else         { P.d1[l] = (unsigned char)(108 + p); P.b1[l] = (unsigned char)pcol[p]; }
      lload[l] = base + th; lnit[l] = it + 1;
    }
    for (int c = 0; c < S; c++) {
      if (ccnt[c] != th) continue;
      const int l = pickLane(th);
      const int it = lnit[l], base = lload[l];
      for (int j = 0; j < th; j++) {
        P.src[l][base + j] = (unsigned char)arow[clist[c][j]];
        if (it == 0) P.a0[l][base + j] = clist[c][j];
        else         P.a1[l][base + j] = clist[c][j];
      }
      if (it == 0) { P.d0[l] = (unsigned char)c; P.b0[l] = (unsigned char)c; }
      else         { P.d1[l] = (unsigned char)c; P.b1[l] = (unsigned char)c; }
      lload[l] = base + th; lnit[l] = it + 1;
    }
  }
  int ml = 0;
  for (int l = 0; l < 64; l++) ml = (lload[l] > ml) ? lload[l] : ml;
  P.maxload = ml; P.ncons = ncons; P.np = np;

  // ---- bank-aware gather-slot permutation ----
  // Per slot e, the 64 lanes' reads hit bank (gsrc%32). Greedily permute each
  // lane's entries so each slot's bank histogram stays flat. Consumer lanes
  // keep slots 0..2 fixed (the x[0..2] sumv contract).
  {
    int bankcnt[MAXG][32] = {};
    for (int l = 0; l < 64; l++) {
      const int efix = (P.scol[l] >= 0) ? 3 : 0;
      for (int e = 0; e < efix; e++) bankcnt[e][P.src[l][e] & 31]++;
      unsigned char ts[MAXG]; short t0[MAXG], t1[MAXG]; bool used[MAXG] = {};
      for (int e = 0; e < MAXG; e++) { ts[e] = P.src[l][e]; t0[e] = P.a0[l][e]; t1[e] = P.a1[l][e]; }
      for (int e = efix; e < MAXG; e++) {
        int best = -1, bestc = 1 << 30;
        for (int j = efix; j < MAXG; j++) {
          if (used[j]) continue;
          const int c = bankcnt[e][ts[j] & 31];
          if (c < bestc) { bestc = c; best = j; }
        }
        used[best] = true;
        P.src[l][e] = ts[best]; P.a0[l][e] = t0[best]; P.a1[l][e] = t1[best];
        bankcnt[e][ts[best] & 31]++;
      }
    }
  }
  return P;
}

constexpr APlan PLAN_HOST = buildPlan();
static_assert(PLAN_HOST.maxload <= MAXG, "lane gather overflow");
static_assert(PLAN_HOST.ncons <= 10, "too many consumer lanes");
static_assert(PLAN_HOST.np <= 14, "piece slots must fit cols 108..121");
__device__ const APlan g_plan = PLAN_HOST;

// One producer step, ring-as-alpha. SYM_: symbol. RS_: ring base of row t.
// GB_: ring base of row t-1 (gather source + scol destination).
// RESC_: rescale flag (uniform; max from x[] = row t-1, overlaps the FMA tree).
// SCOK_: emit split-col write for row t-1. W0_: item0 weights (w0j at j==0).
#define PSTEP(SYM_, RS_, GB_, RESC_, SCOK_, W0_)                          \
  {                                                                       \
    const int ecur_ = (SYM_);                                             \
    float x[MAXG];                                                        \
    _Pragma("unroll")                                                     \
    for (int e = 0; e < MAXG; e++) x[e] = ring[(GB_) + gsrc[e]];          \
    const float bt0_ = Bt_lds[ecur_ * S + b0c];                           \
    const float bt1_ = Bt_lds[ecur_ * S + b1c];                           \
    float aA_ = 0.f, aB_ = 0.f, bA_ = 0.f, bB_ = 0.f;                     \
    _Pragma("unroll")                                                     \
    for (int e = 0; e < MAXG; e += 2) {                                   \
      aA_ += x[e] * W0_[e];     aB_ += x[e + 1] * W0_[e + 1];             \
      bA_ += x[e] * w1v[e];     bB_ += x[e + 1] * w1v[e + 1];             \
    }                                                                     \
    u0 = (aA_ + aB_) * bt0_;                                              \
    u1 = (bA_ + bB_) * bt1_;                                              \
    const float sumv_ = x[0] + sm1 * x[1] + sm2 * x[2];                   \
    if (RESC_) {                                                          \
      float m_ = x[0];                                                    \
      _Pragma("unroll")                                                   \
      for (int e = 1; e < MAXG; e++) m_ = fmaxf(m_, x[e]);                \
      _Pragma("unroll")                                                   \
      for (int msk_ = 1; msk_ < 64; msk_ <<= 1)                           \
        m_ = fmaxf(m_, __shfl_xor(m_, msk_, 64));                        \
      const float r_ = RESCALE_TARGET / m_;                               \
      u0 *= r_; u1 *= r_;                                                 \
    }                                                                     \
    ring[(RS_) + d0] = u0;                                                \
    ring[(RS_) + d1] = u1;                                                \
    if (SCOK_) {                                                          \
      const int a2_ = (scol >= 0) ? (GB_) + scol : (GB_) + 123 + (lid & 3); \
      ring[a2_] = sumv_;                                                  \
    }                                                                     \
  }

// ================= scan kernel: ring-as-alpha producer + light consumer ========
__global__ __launch_bounds__(128, 1) void hmm_scan_kernel(
    const int* __restrict__ inp, const float* __restrict__ w,
    const float* __restrict__ ek, const float* __restrict__ ik,
    float* __restrict__ out) {
  __shared__ __align__(16) float Bt_lds[NEMIT * S];
  __shared__ __align__(16) float ring[32 * RW];      // 32 rows x 132: state+pieces+trash
  __shared__ float pi_lds[S];
  __shared__ float avalS[NE_A];
  __shared__ __align__(16) int seq_lds[T_LEN + 16];  // padded: no bounds select

  const int tid = threadIdx.x;
  const int lid = tid & 63;
  const int wv = tid >> 6;   // 0 = producer, 1 = consumer

  // ---------- setup (both waves cooperate) ----------
  for (int i = tid; i < NEMIT * S; i += 128) Bt_lds[i] = 0.f;

  {  // seq -> LDS (int4 loads); pad
    const int4* s4 = (const int4*)(inp + (size_t)blockIdx.x * T_LEN);
    int4* d4 = (int4*)seq_lds;
    for (int i = tid; i < T_LEN / 4; i += 128) d4[i] = s4[i];
    if (tid < 4) d4[T_LEN / 4 + tid] = s4[T_LEN / 4 - 1];
  }

  if (wv == 0) {  // pi = softmax(ik)
    float q0 = ik[lid];
    float q1 = (lid + 64 < S) ? ik[lid + 64] : -1e30f;
    float mx = fmaxf(q0, q1);
#pragma unroll
    for (int msk = 1; msk < 64; msk <<= 1) mx = fmaxf(mx, __shfl_xor(mx, msk, 64));
    float e0v = expf(q0 - mx);
    float e1v = (lid + 64 < S) ? expf(q1 - mx) : 0.f;
    float zz = e0v + e1v;
#pragma unroll
    for (int msk = 1; msk < 64; msk <<= 1) zz += __shfl_xor(zz, msk, 64);
    const float rz = 1.f / zz;
    pi_lds[lid] = e0v * rz;
    if (lid + 64 < S) pi_lds[lid + 64] = e1v * rz;
  }

  {  // A values from descriptors
    const float wk = w[52];
    const float aw = fabsf(wk);
    const float sgnw = (wk > 0.f) ? 1.f : ((wk < 0.f) ? -1.f : 0.f);
    for (int e = tid; e < NE_A; e += 128) {
      const int code = g_plan.vcode[e];
      const int wi = g_plan.vwi[e];
      float v;
      if (code == 0) v = 1.f;
      else if (code == 1) v = w[wi];
      else if (code == 2) v = 1.f - w[wi];
      else {
        const float pw = powf(aw, (float)wi);
        v = 1.f - ((wi & 1) ? sgnw : 1.f) * pw;
      }
      avalS[e] = v;
    }
  }
  __syncthreads();

  if (tid < S) {  // A row-softmax
    const int b = g_plan.arp[tid], e2 = g_plan.arp[tid + 1];
    float m = -1e30f;
    for (int j = b; j < e2; j++) m = fmaxf(m, avalS[g_plan.aidx[j]]);
    float z = 0.f;
    for (int j = b; j < e2; j++) z += expf(avalS[g_plan.aidx[j]] - m);
    const float rz = 1.f / z;
    for (int j = b; j < e2; j++) {
      const int ii = g_plan.aidx[j];
      avalS[ii] = expf(avalS[ii] - m) * rz;
    }
  }
  __syncthreads();

  if (tid < S) {  // B row-softmax
    const int r = tid;
    const int b = g_em.rp[r], e2 = g_em.rp[r + 1];
    float m = -1e30f;
    for (int e = b; e < e2; e++) {
      const int wi = g_em.widx[e];
      m = fmaxf(m, (wi >= 0) ? ek[wi] : 1.f);
    }
    float z = 0.f;
    for (int e = b; e < e2; e++) {
      const int wi = g_em.widx[e];
      z += expf(((wi >= 0) ? ek[wi] : 1.f) - m);
    }
    const float rz = 1.f / z;
    for (int e = b; e < e2; e++) {
      const int wi = g_em.widx[e];
      Bt_lds[(int)g_em.col[e] * S + r] = expf(((wi >= 0) ? ek[wi] : 1.f) - m) * rz;
    }
  }

  // plan -> registers
  int gsrc[MAXG]; float w0v[MAXG], w1v[MAXG];
#pragma unroll
  for (int e = 0; e < MAXG; e++) {
    gsrc[e] = g_plan.src[lid][e];
    const int a0 = g_plan.a0[lid][e], a1 = g_plan.a1[lid][e];
    w0v[e] = (a0 >= 0) ? avalS[a0] : 0.f;
    w1v[e] = (a1 >= 0) ? avalS[a1] : 0.f;
  }
  const int d0 = g_plan.d0[lid], d1 = g_plan.d1[lid];
  const int b0c = g_plan.b0[lid], b1c = g_plan.b1[lid];
  const int scol = g_plan.scol[lid];
  const float sm1 = (float)g_plan.sm1[lid], sm2 = (float)g_plan.sm2[lid];

  // j==0 weights: at group boundaries the source row's split-state slot holds
  // the FULL value, so consumer lanes must not add the piece slots again.
  float w0j[MAXG];
#pragma unroll
  for (int e = 0; e < MAXG; e++) w0j[e] = w0v[e];
  if (scol >= 0) { w0j[1] = 0.f; w0j[2] = 0.f; }
  __syncthreads();   // Bt_lds, avalS, seq_lds final

  float* ob = out + (size_t)blockIdx.x * T_LEN * S;
  int etn = 0;
  float u0 = 0.f, u1 = 0.f;

  if (wv == 0) {  // init: row 0 directly into ring (pieces get 0)
    const int e0s = seq_lds[0];
    const float ui0 = (d0 < 108) ? RESCALE_TARGET * pi_lds[d0] * Bt_lds[e0s * S + d0] : 0.f;
    const float ui1 = (d1 < 108) ? RESCALE_TARGET * pi_lds[d1] * Bt_lds[e0s * S + d1] : 0.f;
    ring[d0] = ui0;
    ring[d1] = ui1;
    etn = seq_lds[1];
  }

  // ---------- main: producer fills group k (k<128); consumer drains+normalizes
  // ---------- group k-1; one barrier per group; rescale at every group tail ---
  for (int k = 0; k <= 128; k++) {
    if (wv == 0) {
      if (k < 128) {
        const int tb = 16 * k;
        const int hb = (k & 1) << 4;
        int rs = hb * RW;
        if (k == 0) {
          rs += RW;   // t starts at 1
          for (int j = 1; j < 15; j++) {
            const int ec = etn; etn = seq_lds[j + 1];
            PSTEP(ec, rs, rs - RW, 0, 1, w0v)
            rs += RW;
          }
          const int ec = etn; etn = seq_lds[16];
          PSTEP(ec, rs, rs - RW, 1, 1, w0v)
        } else {
          const int gb0 = (((k & 1) ^ 1) * 16 + 15) * RW;   // other half's last row
          {  // j = 0: source row holds FULL split-state values -> w0j weights
            const int ec = etn; etn = seq_lds[tb + 1];
            PSTEP(ec, rs, gb0, 0, 0, w0j)
            rs += RW;
          }
          for (int j = 1; j < 15; j++) {
            const int ec = etn; etn = seq_lds[tb + j + 1];
            PSTEP(ec, rs, rs - RW, 0, 1, w0v)
            rs += RW;
          }
          const int ec = etn; etn = seq_lds[tb + 16];
          PSTEP(ec, rs, rs - RW, 1, 1, w0v)
        }
        if (scol >= 0) {  // end-of-group: full split-state value for last row
          const int base = (hb + 15) * RW;
          const float x0 = ring[base + gsrc[0]];
          const float x1 = ring[base + gsrc[1]];
          const float x2 = ring[base + gsrc[2]];
          ring[base + scol] = x0 + sm1 * x1 + sm2 * x2;
        }
      }
    } else {
      if (k > 0) {  // drain + normalize group k-1 (other ring half)
        const int g = k - 1;
        const float4* srcb4 = (const float4*)&ring[(g & 1) * 16 * RW];
        float4* dstb4 = (float4*)(ob + (size_t)g * 16 * S);
        const int r = lid >> 2;
        const int j = lid & 3;
        float4 v0, v1, v2, v3, v4, v5, v6;
        v6 = make_float4(0.f, 0.f, 0.f, 0.f);
        const int sbase = r * 33 + j;   // RW/4 = 33 float4 per ring row
        const int dbase = r * 27 + j;   // S/4 = 27 float4 per output row
        v0 = srcb4[sbase];
        v1 = srcb4[sbase + 4];
        v2 = srcb4[sbase + 8];
        v3 = srcb4[sbase + 12];
        v4 = srcb4[sbase + 16];
        v5 = srcb4[sbase + 20];
        if (j < 3) v6 = srcb4[sbase + 24];
        float psum = v0.x + v0.y + v0.z + v0.w + v1.x + v1.y + v1.z + v1.w
                   + v2.x + v2.y + v2.z + v2.w + v3.x + v3.y + v3.z + v3.w
                   + v4.x + v4.y + v4.z + v4.w + v5.x + v5.y + v5.z + v5.w
                   + v6.x + v6.y + v6.z + v6.w;
        psum += __shfl_xor(psum, 1, 64);
        psum += __shfl_xor(psum, 2, 64);
        const float iv = 1.f / psum;
        v0.x *= iv; v0.y *= iv; v0.z *= iv; v0.w *= iv;
        v1.x *= iv; v1.y *= iv; v1.z *= iv; v1.w *= iv;
        v2.x *= iv; v2.y *= iv; v2.z *= iv; v2.w *= iv;
        v3.x *= iv; v3.y *= iv; v3.z *= iv; v3.w *= iv;
        v4.x *= iv; v4.y *= iv; v4.z *= iv; v4.w *= iv;
        v5.x *= iv; v5.y *= iv; v5.z *= iv; v5.w *= iv;
        v6.x *= iv; v6.y *= iv; v6.z *= iv; v6.w *= iv;
        dstb4[dbase] = v0;
        dstb4[dbase + 4] = v1;
        dstb4[dbase + 8] = v2;
        dstb4[dbase + 12] = v3;
        dstb4[dbase + 16] = v4;
        dstb4[dbase + 20] = v5;
        if (j < 3) dstb4[dbase + 24] = v6;
      }
    }
    __syncthreads();
  }
}

extern "C" void kernel_launch(void* const* d_in, const int* in_sizes, int n_in,
                              void* d_out, int out_size, void* d_ws, size_t ws_size,
                              hipStream_t stream) {
  const int* inp = (const int*)d_in[0];
  const float* w = (const float*)d_in[1];
  const float* ek = (const float*)d_in[2];
  const float* ik = (const float*)d_in[3];
  float* out = (float*)d_out;
  (void)d_ws; (void)ws_size; (void)in_sizes; (void)n_in; (void)out_size;
  hmm_scan_kernel<<<N_BATCH, 128, 0, stream>>>(inp, w, ek, ik, out);
}